// Round 1
// baseline (287.571 us; speedup 1.0000x reference)
//
#include <hip/hip_runtime.h>
#include <hip/hip_bf16.h>
#include <stdint.h>

#define NTOK 8192
#define XSTRIDE 259
#define LOG2E 1.4426950408889634f
#define DECC (-3.4712336270551023f)   /* -4 + log2(log2 e) */
#define KSPLIT 8
#define SPLEN (NTOK / KSPLIT)   /* 1024 */
#define BN 32
#define ITERS (SPLEN / BN)      /* 32 */

typedef __bf16 bf16x8 __attribute__((ext_vector_type(8)));
typedef float f32x4 __attribute__((ext_vector_type(4)));
typedef float f32x16 __attribute__((ext_vector_type(16)));
typedef unsigned short u16;

union BF8 { u16 u[8]; bf16x8 v; };
union PW  { uint32_t u[4]; bf16x8 v; };

__device__ __forceinline__ u16 f2bf(float f) {
  uint32_t u = __float_as_uint(f);
  u += 0x7FFFu + ((u >> 16) & 1u);
  return (u16)(u >> 16);
}
__device__ __forceinline__ float bf2f(u16 h) {
  return __uint_as_float(((uint32_t)h) << 16);
}
__device__ __forceinline__ float exp2_hw(float x) {
  float r; asm("v_exp_f32 %0, %1" : "=v"(r) : "v"(x)); return r;
}
__device__ __forceinline__ f32x4 mfma16(bf16x8 a, bf16x8 b, f32x4 c) {
  return __builtin_amdgcn_mfma_f32_16x16x32_bf16(a, b, c, 0, 0, 0);
}
__device__ __forceinline__ f32x16 mfma32(bf16x8 a, bf16x8 b, f32x16 c) {
  return __builtin_amdgcn_mfma_f32_32x32x16_bf16(a, b, c, 0, 0, 0);
}
__device__ __forceinline__ void async16(const void* g, void* l) {
  __builtin_amdgcn_global_load_lds(
      (const __attribute__((address_space(1))) uint32_t*)g,
      (__attribute__((address_space(3))) uint32_t*)l, 16, 0, 0);
}

// ---------------------------------------------------------------------------
// Kernel 0: pq[row] = (px, py, pz, 0.5*|P|^2)
// ---------------------------------------------------------------------------
__global__ void pq_kernel(const float* __restrict__ X, float* __restrict__ pq) {
  int r = blockIdx.x * 256 + threadIdx.x;
  const float* xp = X + (size_t)r * XSTRIDE + 256;
  float x = xp[0], y = xp[1], z = xp[2];
  f32x4 o = { x, y, z, 0.5f * (x * x + y * y + z * z) };
  ((f32x4*)pq)[r] = o;
}

// ---------------------------------------------------------------------------
// Kernel 0b: W^T bf16 prep. Wt[o_global][k] = bf16(W[k][o]).
// ---------------------------------------------------------------------------
__global__ __launch_bounds__(256) void wprep_kernel(
    const float* __restrict__ WQ, const float* __restrict__ WK,
    const float* __restrict__ WV, u16* __restrict__ Wt) {
  const int o = blockIdx.x;          // 0..767
  const int which = o >> 8, oo = o & 255;
  const float* W = (which == 0) ? WQ : ((which == 1) ? WK : WV);
  const int k = threadIdx.x;
  Wt[(size_t)o * 256 + k] = f2bf(W[(size_t)k * 256 + oo]);
}

// ---------------------------------------------------------------------------
// Kernel 1: QKV projection.  grid (64 rowblocks, 12 col-chunks).
//  Q is now written in 32x32x16-MFMA B-fragment layout so the attn prologue
//  can load it fully coalesced:
//    Qb[((row>>5)*16 + (col>>4))*512 + ((col>>3)&1)*256 + (row&31)*8 + (col&7)]
// ---------------------------------------------------------------------------
__global__ __launch_bounds__(256) void qkv_kernel(
    const float* __restrict__ X, const u16* __restrict__ Wt,
    const float* __restrict__ bQ, const float* __restrict__ bK,
    const float* __restrict__ bV,
    u16* __restrict__ Qb, u16* __restrict__ Kb, u16* __restrict__ Vt) {
  __shared__ u16 wt[64 * 256];
  const int tid = threadIdx.x;
  const int lane = tid & 63;
  const int wave = tid >> 6;
  const int l15 = lane & 15;
  const int q4 = lane >> 4;
  const int rb = blockIdx.x;
  const int ch = blockIdx.y;
  const int which = ch >> 2;
  const int c0 = (ch & 3) * 64;
  const float* bias = (which == 0) ? bQ : ((which == 1) ? bK : bV);

  bf16x8 xa[2][8];
#pragma unroll
  for (int mt = 0; mt < 2; ++mt) {
    const int row = rb * 128 + wave * 32 + mt * 16 + l15;
#pragma unroll
    for (int kc = 0; kc < 8; ++kc) {
      const float* xp = X + (size_t)row * XSTRIDE + kc * 32 + q4 * 8;
      BF8 u;
#pragma unroll
      for (int jj = 0; jj < 8; ++jj) u.u[jj] = f2bf(xp[jj]);
      xa[mt][kc] = u.v;
    }
  }
  {
    const u16* Wsrc = Wt + (size_t)(which * 256 + c0) * 256;
    const int rb0 = wave * 16;
#pragma unroll
    for (int i = 0; i < 8; ++i) {
      int r = rb0 + i * 2 + (lane >> 5);
      int c = (lane & 31) ^ (r & 7);
      async16(Wsrc + (size_t)r * 256 + c * 8, wt + (rb0 + i * 2) * 256);
    }
  }
  asm volatile("s_waitcnt vmcnt(0)" ::: "memory");
  __syncthreads();

  f32x4 acc[2][4];
#pragma unroll
  for (int mt = 0; mt < 2; ++mt)
#pragma unroll
    for (int nt = 0; nt < 4; ++nt) acc[mt][nt] = (f32x4){0.f, 0.f, 0.f, 0.f};

#pragma unroll
  for (int kc = 0; kc < 8; ++kc) {
#pragma unroll
    for (int nt = 0; nt < 4; ++nt) {
      bf16x8 wf = *(const bf16x8*)(wt + (nt * 16 + l15) * 256 +
                                   (((kc * 4 + q4) ^ (l15 & 7)) * 8));
#pragma unroll
      for (int mt = 0; mt < 2; ++mt)
        acc[mt][nt] = mfma16(xa[mt][kc], wf, acc[mt][nt]);
    }
  }
  float bc[4];
#pragma unroll
  for (int nt = 0; nt < 4; ++nt) bc[nt] = bias[c0 + nt * 16 + l15];

#pragma unroll
  for (int mt = 0; mt < 2; ++mt)
#pragma unroll
    for (int nt = 0; nt < 4; ++nt)
#pragma unroll
      for (int r = 0; r < 4; ++r) {
        float v = acc[mt][nt][r] + bc[nt];
        int grow = rb * 128 + wave * 32 + mt * 16 + q4 * 4 + r;
        int gc = c0 + nt * 16 + l15;
        if (which == 2)      Vt[(size_t)gc * NTOK + grow] = f2bf(v);
        else if (which == 1) Kb[(size_t)grow * 256 + gc] = f2bf(v);
        else                 Qb[(size_t)((grow >> 5) * 16 + (gc >> 4)) * 512 +
                                ((gc >> 3) & 1) * 256 + (grow & 31) * 8 +
                                (gc & 7)] = f2bf(v);
      }
}

// ---------------------------------------------------------------------------
// Kernel 2: flash attention, 32x32x16 MFMA, M=32 rows/wave.
//  grid (8 sp, 64 rb) = 512 blocks = 2/CU; linear%8 = sp -> split-per-XCD
//  so each XCD's 1MB K/V slice is L2-resident.
//  Per wave/iter: S^T = mfma(K, Q^T) (16 MFMA, K-frags from LDS, Q in regs);
//  decay+exp per-lane (col=lane&31 = qrow -> query pos in 4 scalars);
//  P packed to bf16 A-frags IN REGISTERS via v_cvt_pk_bf16_f32 +
//  v_permlane32_swap_b32 (no pbuf, no extra fences); O += P·V (16 MFMA).
//  LDS bytes/FLOP halved vs the 16-row version (the measured bottleneck).
//  V store swizzle is ((f>>1)&3) (NOT f&3): 32 feature-lanes/read need it
//  to hit the 8-lanes-per-bank-quad service floor.
// ---------------------------------------------------------------------------
__global__ __launch_bounds__(256, 2) void attn_kernel(
    const u16* __restrict__ Qb, const u16* __restrict__ Kb,
    const u16* __restrict__ Vt, const float* __restrict__ pq,
    u16* __restrict__ Op, float* __restrict__ ml) {
  __shared__ u16 kbuf[2][BN * 256];               // 16 KB x2  [key][256]
  __shared__ u16 vbuf[2][256 * BN];               // 16 KB x2  [feat][32]
  __shared__ __align__(16) float pqk[2][BN * 4];  // 512 B x2

  const int tid = threadIdx.x;
  const int lane = tid & 63;
  const int wave = tid >> 6;
  const int l31 = lane & 31;
  const int h5 = lane >> 5;
  const int sp = blockIdx.x;
  const int rb = blockIdx.y;
  const int q0 = rb * 128;
  const int wrow = wave * 32;

#define STAGE(T)                                                              \
  do {                                                                        \
    const int key0_ = sp * SPLEN + (T) * BN;                                  \
    const int b_ = (T) & 1;                                                   \
    if (wave < 2) {                                                           \
      const int rb0 = wave * 16;                                              \
      _Pragma("unroll")                                                       \
      for (int i = 0; i < 8; ++i) {                                           \
        int r = rb0 + i * 2 + (lane >> 5);                                    \
        int c = (lane & 31) ^ (r & 7);                                        \
        async16(Kb + (size_t)(key0_ + r) * 256 + c * 8,                       \
                &kbuf[b_][(rb0 + i * 2) * 256]);                              \
      }                                                                       \
      if (wave == 1 && lane < 32)                                             \
        async16(((const f32x4*)pq) + key0_ + lane, &pqk[b_][0]);              \
    } else {                                                                  \
      const int fb0 = (wave - 2) * 128;                                       \
      _Pragma("unroll")                                                       \
      for (int i = 0; i < 8; ++i) {                                           \
        int f = fb0 + i * 16 + (lane >> 2);                                   \
        int c = (lane & 3) ^ ((f >> 1) & 3);                                  \
        async16(Vt + (size_t)f * NTOK + key0_ + c * 8,                        \
                &vbuf[b_][(fb0 + i * 16) * 32]);                              \
      }                                                                       \
    }                                                                         \
  } while (0)

  // ---- Q fragments (loop-invariant, fully coalesced from frag-layout Qb) --
  const int rb32 = rb * 4 + wave;
  bf16x8 qa[16];
#pragma unroll
  for (int kc = 0; kc < 16; ++kc)
    qa[kc] = *(const bf16x8*)(Qb + ((size_t)(rb32 * 16 + kc) * 64 + lane) * 8);

  // query position for this lane's qrow (col = lane&31 in S^T layout)
  f32x4 prv = ((const f32x4*)pq)[q0 + wrow + l31];
  const float nprx = -prv[0], npry = -prv[1], nprz = -prv[2], prw = prv[3];

  f32x16 O[8];
#pragma unroll
  for (int ft = 0; ft < 8; ++ft)
#pragma unroll
    for (int r = 0; r < 16; ++r) O[ft][r] = 0.f;
  float lrow = 0.f;

  const int kswz = l31 & 7;
  const int vswz = (l31 >> 1) & 3;

  STAGE(0);

#pragma unroll 1
  for (int it = 0; it < ITERS; ++it) {
    const int cur = it & 1;
    asm volatile("s_waitcnt vmcnt(0)" ::: "memory");
    __syncthreads();

    const int nx = (it + 1 < ITERS) ? (it + 1) : (ITERS - 1);
    STAGE(nx);

    // ---- S^T = K Q^T : D[key][qrow], 32 keys x 32 rows, once per wave ----
    f32x16 S;
#pragma unroll
    for (int r = 0; r < 16; ++r) S[r] = 0.f;
#pragma unroll
    for (int kc = 0; kc < 16; ++kc) {
      bf16x8 kf = *(const bf16x8*)(&kbuf[cur][l31 * 256 +
                                   (((2 * kc + h5) ^ kswz) * 8)]);
      S = mfma32(kf, qa[kc], S);
    }

    // ---- decay + exp (key = (r&3)+8*(r>>2)+4*h5; pk broadcast reads) ----
#pragma unroll
    for (int r = 0; r < 16; ++r) {
      f32x4 pk = ((const f32x4*)pqk[cur])[(r & 3) + 8 * (r >> 2) + 4 * h5];
      float t = pk[3] + prw;
      t = fmaf(nprx, pk[0], t);
      t = fmaf(npry, pk[1], t);
      t = fmaf(nprz, pk[2], t);
      float dec = exp2_hw(fmaf(t, -LOG2E, DECC));
      float p = exp2_hw(S[r] * dec);
      S[r] = p;
      lrow += p;
    }

    // ---- pack P to bf16 A-frags in-register (cvt_pk + permlane32_swap) ----
    uint32_t w0, w1, w2, w3, w4, w5, w6, w7;
    asm("v_cvt_pk_bf16_f32 %0, %1, %2" : "=v"(w0) : "v"(S[0]),  "v"(S[1]));
    asm("v_cvt_pk_bf16_f32 %0, %1, %2" : "=v"(w1) : "v"(S[2]),  "v"(S[3]));
    asm("v_cvt_pk_bf16_f32 %0, %1, %2" : "=v"(w2) : "v"(S[4]),  "v"(S[5]));
    asm("v_cvt_pk_bf16_f32 %0, %1, %2" : "=v"(w3) : "v"(S[6]),  "v"(S[7]));
    asm("v_cvt_pk_bf16_f32 %0, %1, %2" : "=v"(w4) : "v"(S[8]),  "v"(S[9]));
    asm("v_cvt_pk_bf16_f32 %0, %1, %2" : "=v"(w5) : "v"(S[10]), "v"(S[11]));
    asm("v_cvt_pk_bf16_f32 %0, %1, %2" : "=v"(w6) : "v"(S[12]), "v"(S[13]));
    asm("v_cvt_pk_bf16_f32 %0, %1, %2" : "=v"(w7) : "v"(S[14]), "v"(S[15]));
    // exchange lo-half of first op with hi-half of second op:
    // after swap(w2,w0): w0 = keys(0,1)|(8,9) word0, w2 = keys(4,5)|(12,13) word2
    asm volatile("v_permlane32_swap_b32 %0, %1" : "+v"(w2), "+v"(w0));
    asm volatile("v_permlane32_swap_b32 %0, %1" : "+v"(w3), "+v"(w1));
    asm volatile("v_permlane32_swap_b32 %0, %1" : "+v"(w6), "+v"(w4));
    asm volatile("v_permlane32_swap_b32 %0, %1" : "+v"(w7), "+v"(w5));
    PW pa0, pa1;
    pa0.u[0] = w0; pa0.u[1] = w1; pa0.u[2] = w2; pa0.u[3] = w3;  // keys 0..15
    pa1.u[0] = w4; pa1.u[1] = w5; pa1.u[2] = w6; pa1.u[3] = w7;  // keys 16..31

    // ---- O += P V (full 256 features, 8 ft-blocks of 32) ----
#pragma unroll
    for (int kh = 0; kh < 2; ++kh) {
      const bf16x8 pa = kh ? pa1.v : pa0.v;
#pragma unroll
      for (int ft = 0; ft < 8; ++ft) {
        bf16x8 vf = *(const bf16x8*)(&vbuf[cur][(ft * 32 + l31) * 32 +
                                     (((2 * kh + h5) ^ vswz) * 8)]);
        O[ft] = mfma32(pa, vf, O[ft]);
      }
    }
  }

  // ---- epilogue ----
  float lsum = lrow + __shfl_xor(lrow, 32);
#pragma unroll
  for (int ft = 0; ft < 8; ++ft)
#pragma unroll
    for (int r = 0; r < 16; ++r) {
      int row = q0 + wrow + (r & 3) + 8 * (r >> 2) + 4 * h5;
      Op[((size_t)sp * NTOK + row) * 256 + ft * 32 + l31] = f2bf(O[ft][r]);
    }
  if (lane < 32)
    ml[sp * NTOK + q0 + wrow + lane] = lsum;
#undef STAGE
}

// ---------------------------------------------------------------------------
// Kernel 3: combine splits: H = (sum O_s) / (1 + sum l_s) + residual.
// ---------------------------------------------------------------------------
__global__ __launch_bounds__(256) void combine_kernel(
    const float* __restrict__ X, const u16* __restrict__ Op,
    const float* __restrict__ ml, float* __restrict__ out) {
  const int row = blockIdx.x;
  const int f = threadIdx.x;
  float den = 1.f, num = 0.f;
#pragma unroll
  for (int s = 0; s < KSPLIT; ++s) {
    den += ml[s * NTOK + row];
    num += bf2f(Op[((size_t)s * NTOK + row) * 256 + f]);
  }
  out[(size_t)row * 256 + f] = num / den + X[(size_t)row * XSTRIDE + f];
}

// ---------------------------------------------------------------------------
extern "C" void kernel_launch(void* const* d_in, const int* in_sizes, int n_in,
                              void* d_out, int out_size, void* d_ws, size_t ws_size,
                              hipStream_t stream) {
  (void)in_sizes; (void)n_in; (void)out_size; (void)ws_size;
  const float* X  = (const float*)d_in[0];
  const float* WQ = (const float*)d_in[1];
  const float* bQ = (const float*)d_in[2];
  const float* WK = (const float*)d_in[3];
  const float* bK = (const float*)d_in[4];
  const float* WV = (const float*)d_in[5];
  const float* bV = (const float*)d_in[6];
  float* out = (float*)d_out;
  char* ws = (char*)d_ws;

  // ws: Qb 4M | Kb 4M | Vt 4M | pq 128K | Wt 384K | Op 32M | ml 256K (~45 MB)
  u16*   Qb = (u16*)(ws);
  u16*   Kb = (u16*)(ws + ((size_t)4 << 20));
  u16*   Vt = (u16*)(ws + ((size_t)8 << 20));
  float* pq = (float*)(ws + ((size_t)12 << 20));
  u16*   Wt = (u16*)(ws + ((size_t)12 << 20) + 131072);
  u16*   Op = (u16*)(ws + ((size_t)12 << 20) + 131072 + 393216);
  float* ml = (float*)(ws + ((size_t)12 << 20) + 131072 + 393216 +
                       (size_t)KSPLIT * NTOK * 256 * 2);

  pq_kernel<<<dim3(NTOK / 256), dim3(256), 0, stream>>>(X, pq);
  wprep_kernel<<<dim3(768), dim3(256), 0, stream>>>(WQ, WK, WV, Wt);
  qkv_kernel<<<dim3(64, 12), dim3(256), 0, stream>>>(X, Wt, bQ, bK, bV,
                                                     Qb, Kb, Vt);
  attn_kernel<<<dim3(KSPLIT, NTOK / 128), dim3(256), 0, stream>>>(
      Qb, Kb, Vt, pq, Op, ml);
  combine_kernel<<<dim3(NTOK), dim3(256), 0, stream>>>(X, Op, ml, out);
}

// Round 2
// 269.990 us; speedup vs baseline: 1.0651x; 1.0651x over previous
//
#include <hip/hip_runtime.h>
#include <hip/hip_bf16.h>
#include <stdint.h>

#define NTOK 8192
#define XSTRIDE 259
#define LOG2E 1.4426950408889634f
#define DECC (-3.4712336270551023f)   /* -4 + log2(log2 e) */
#define KSPLIT 8
#define SPLEN (NTOK / KSPLIT)   /* 1024 */
#define BN 32
#define ITERS (SPLEN / BN)      /* 32 */

typedef __bf16 bf16x8 __attribute__((ext_vector_type(8)));
typedef float f32x4 __attribute__((ext_vector_type(4)));
typedef float f32x16 __attribute__((ext_vector_type(16)));
typedef unsigned short u16;

union BF8 { u16 u[8]; bf16x8 v; };
union PW  { uint32_t u[4]; bf16x8 v; };

__device__ __forceinline__ u16 f2bf(float f) {
  uint32_t u = __float_as_uint(f);
  u += 0x7FFFu + ((u >> 16) & 1u);
  return (u16)(u >> 16);
}
__device__ __forceinline__ float bf2f(u16 h) {
  return __uint_as_float(((uint32_t)h) << 16);
}
__device__ __forceinline__ float exp2_hw(float x) {
  float r; asm("v_exp_f32 %0, %1" : "=v"(r) : "v"(x)); return r;
}
__device__ __forceinline__ f32x4 mfma16(bf16x8 a, bf16x8 b, f32x4 c) {
  return __builtin_amdgcn_mfma_f32_16x16x32_bf16(a, b, c, 0, 0, 0);
}
__device__ __forceinline__ f32x16 mfma32(bf16x8 a, bf16x8 b, f32x16 c) {
  return __builtin_amdgcn_mfma_f32_32x32x16_bf16(a, b, c, 0, 0, 0);
}
__device__ __forceinline__ void async16(const void* g, void* l) {
  __builtin_amdgcn_global_load_lds(
      (const __attribute__((address_space(1))) uint32_t*)g,
      (__attribute__((address_space(3))) uint32_t*)l, 16, 0, 0);
}
__device__ __forceinline__ void bsplit(float v, u16& h, u16& l) {
  h = f2bf(v);
  l = f2bf(v - bf2f(h));
}

// ---------------------------------------------------------------------------
// Kernel 0: position feature vectors for the MFMA-computed decay exponent.
//  t(q,k) = w_q + w_k - x_q x_k - y_q y_k - z_q z_k  (w = 0.5|p|^2)
//  encoded as a 13-dim bf16 dot (hi/lo split per float; lo*lo terms dropped,
//  error ~1e-4 << tolerance). Qp = q-side vec, Kp = k-side vec, [NTOK][16].
// ---------------------------------------------------------------------------
__global__ __launch_bounds__(256) void pos_kernel(
    const float* __restrict__ X, u16* __restrict__ Qp, u16* __restrict__ Kp) {
  const int r = blockIdx.x * 256 + threadIdx.x;
  const float* xp = X + (size_t)r * XSTRIDE + 256;
  const float x = xp[0], y = xp[1], z = xp[2];
  const float w = 0.5f * (x * x + y * y + z * z);
  u16 xh, xl, yh, yl, zh, zl, wh, wl;
  bsplit(x, xh, xl); bsplit(y, yh, yl); bsplit(z, zh, zl); bsplit(w, wh, wl);
  const u16 one = 0x3F80u;
  const u16 SGN = 0x8000u;
  union { u16 u[16]; uint4 v4[2]; } uq, uk;
  // pairing per dim i: t += q[i]*k[i]
  uq.u[0] = wh;  uk.u[0] = one;   // w_q
  uq.u[1] = wl;  uk.u[1] = one;
  uq.u[2] = one; uk.u[2] = wh;    // w_k
  uq.u[3] = one; uk.u[3] = wl;
  uq.u[4] = (u16)(xh ^ SGN); uk.u[4] = xh;   // -x_q x_k
  uq.u[5] = (u16)(xh ^ SGN); uk.u[5] = xl;
  uq.u[6] = (u16)(xl ^ SGN); uk.u[6] = xh;
  uq.u[7] = (u16)(yh ^ SGN); uk.u[7] = yh;   // -y_q y_k
  uq.u[8] = (u16)(yh ^ SGN); uk.u[8] = yl;
  uq.u[9] = (u16)(yl ^ SGN); uk.u[9] = yh;
  uq.u[10] = (u16)(zh ^ SGN); uk.u[10] = zh; // -z_q z_k
  uq.u[11] = (u16)(zh ^ SGN); uk.u[11] = zl;
  uq.u[12] = (u16)(zl ^ SGN); uk.u[12] = zh;
  uq.u[13] = 0; uk.u[13] = 0;
  uq.u[14] = 0; uk.u[14] = 0;
  uq.u[15] = 0; uk.u[15] = 0;
  ((uint4*)Qp)[r * 2] = uq.v4[0];
  ((uint4*)Qp)[r * 2 + 1] = uq.v4[1];
  ((uint4*)Kp)[r * 2] = uk.v4[0];
  ((uint4*)Kp)[r * 2 + 1] = uk.v4[1];
}

// ---------------------------------------------------------------------------
// Kernel 0b: W^T bf16 prep. Wt[o_global][k] = bf16(W[k][o]).
// ---------------------------------------------------------------------------
__global__ __launch_bounds__(256) void wprep_kernel(
    const float* __restrict__ WQ, const float* __restrict__ WK,
    const float* __restrict__ WV, u16* __restrict__ Wt) {
  const int o = blockIdx.x;          // 0..767
  const int which = o >> 8, oo = o & 255;
  const float* W = (which == 0) ? WQ : ((which == 1) ? WK : WV);
  const int k = threadIdx.x;
  Wt[(size_t)o * 256 + k] = f2bf(W[(size_t)k * 256 + oo]);
}

// ---------------------------------------------------------------------------
// Kernel 1: QKV projection.  grid (64 rowblocks, 12 col-chunks).
//  Q written in 32x32x16-MFMA B-fragment layout (coalesced attn prologue).
// ---------------------------------------------------------------------------
__global__ __launch_bounds__(256) void qkv_kernel(
    const float* __restrict__ X, const u16* __restrict__ Wt,
    const float* __restrict__ bQ, const float* __restrict__ bK,
    const float* __restrict__ bV,
    u16* __restrict__ Qb, u16* __restrict__ Kb, u16* __restrict__ Vt) {
  __shared__ u16 wt[64 * 256];
  const int tid = threadIdx.x;
  const int lane = tid & 63;
  const int wave = tid >> 6;
  const int l15 = lane & 15;
  const int q4 = lane >> 4;
  const int rb = blockIdx.x;
  const int ch = blockIdx.y;
  const int which = ch >> 2;
  const int c0 = (ch & 3) * 64;
  const float* bias = (which == 0) ? bQ : ((which == 1) ? bK : bV);

  bf16x8 xa[2][8];
#pragma unroll
  for (int mt = 0; mt < 2; ++mt) {
    const int row = rb * 128 + wave * 32 + mt * 16 + l15;
#pragma unroll
    for (int kc = 0; kc < 8; ++kc) {
      const float* xp = X + (size_t)row * XSTRIDE + kc * 32 + q4 * 8;
      BF8 u;
#pragma unroll
      for (int jj = 0; jj < 8; ++jj) u.u[jj] = f2bf(xp[jj]);
      xa[mt][kc] = u.v;
    }
  }
  {
    const u16* Wsrc = Wt + (size_t)(which * 256 + c0) * 256;
    const int rb0 = wave * 16;
#pragma unroll
    for (int i = 0; i < 8; ++i) {
      int r = rb0 + i * 2 + (lane >> 5);
      int c = (lane & 31) ^ (r & 7);
      async16(Wsrc + (size_t)r * 256 + c * 8, wt + (rb0 + i * 2) * 256);
    }
  }
  asm volatile("s_waitcnt vmcnt(0)" ::: "memory");
  __syncthreads();

  f32x4 acc[2][4];
#pragma unroll
  for (int mt = 0; mt < 2; ++mt)
#pragma unroll
    for (int nt = 0; nt < 4; ++nt) acc[mt][nt] = (f32x4){0.f, 0.f, 0.f, 0.f};

#pragma unroll
  for (int kc = 0; kc < 8; ++kc) {
#pragma unroll
    for (int nt = 0; nt < 4; ++nt) {
      bf16x8 wf = *(const bf16x8*)(wt + (nt * 16 + l15) * 256 +
                                   (((kc * 4 + q4) ^ (l15 & 7)) * 8));
#pragma unroll
      for (int mt = 0; mt < 2; ++mt)
        acc[mt][nt] = mfma16(xa[mt][kc], wf, acc[mt][nt]);
    }
  }
  float bc[4];
#pragma unroll
  for (int nt = 0; nt < 4; ++nt) bc[nt] = bias[c0 + nt * 16 + l15];

#pragma unroll
  for (int mt = 0; mt < 2; ++mt)
#pragma unroll
    for (int nt = 0; nt < 4; ++nt)
#pragma unroll
      for (int r = 0; r < 4; ++r) {
        float v = acc[mt][nt][r] + bc[nt];
        int grow = rb * 128 + wave * 32 + mt * 16 + q4 * 4 + r;
        int gc = c0 + nt * 16 + l15;
        if (which == 2)      Vt[(size_t)gc * NTOK + grow] = f2bf(v);
        else if (which == 1) Kb[(size_t)grow * 256 + gc] = f2bf(v);
        else                 Qb[(size_t)((grow >> 5) * 16 + (gc >> 4)) * 512 +
                                ((gc >> 3) & 1) * 256 + (grow & 31) * 8 +
                                (gc & 7)] = f2bf(v);
      }
}

// ---------------------------------------------------------------------------
// Kernel 2: flash attention, 32x32x16 MFMA, M=32 rows/wave.
//  R1 regression root-cause: softmax phase had 16 serialized broadcast LDS
//  reads + dep chains, unhoistable at ~250/256 reg pressure. Fix: the decay
//  exponent t is bilinear -> computed by ONE extra MFMA (T = kp x qp) whose
//  output is element-aligned with S. No in-loop pqk reads, softmax is
//  5 VALU/score. s_setprio(1) wraps MFMA clusters (T5).
// ---------------------------------------------------------------------------
__global__ __launch_bounds__(256, 2) void attn_kernel(
    const u16* __restrict__ Qb, const u16* __restrict__ Kb,
    const u16* __restrict__ Vt, const u16* __restrict__ Qp,
    const u16* __restrict__ Kp, u16* __restrict__ Op,
    float* __restrict__ ml) {
  __shared__ u16 kbuf[2][BN * 256];               // 16 KB x2  [key][256]
  __shared__ u16 vbuf[2][256 * BN];               // 16 KB x2  [feat][32]
  __shared__ u16 kpbuf[2][BN * 16];               // 1 KB x2   [key][16]

  const int tid = threadIdx.x;
  const int lane = tid & 63;
  const int wave = tid >> 6;
  const int l31 = lane & 31;
  const int h5 = lane >> 5;
  const int sp = blockIdx.x;
  const int rb = blockIdx.y;
  const int q0 = rb * 128;
  const int wrow = wave * 32;

#define STAGE(T)                                                              \
  do {                                                                        \
    const int key0_ = sp * SPLEN + (T) * BN;                                  \
    const int b_ = (T) & 1;                                                   \
    if (wave < 2) {                                                           \
      const int rb0 = wave * 16;                                              \
      _Pragma("unroll")                                                       \
      for (int i = 0; i < 8; ++i) {                                           \
        int r = rb0 + i * 2 + (lane >> 5);                                    \
        int c = (lane & 31) ^ (r & 7);                                        \
        async16(Kb + (size_t)(key0_ + r) * 256 + c * 8,                       \
                &kbuf[b_][(rb0 + i * 2) * 256]);                              \
      }                                                                       \
      if (wave == 1)                                                          \
        async16(Kp + (size_t)(key0_ + (lane >> 1)) * 16 + (lane & 1) * 8,     \
                &kpbuf[b_][0]);                                               \
    } else {                                                                  \
      const int fb0 = (wave - 2) * 128;                                       \
      _Pragma("unroll")                                                       \
      for (int i = 0; i < 8; ++i) {                                           \
        int f = fb0 + i * 16 + (lane >> 2);                                   \
        int c = (lane & 3) ^ ((f >> 1) & 3);                                  \
        async16(Vt + (size_t)f * NTOK + key0_ + c * 8,                        \
                &vbuf[b_][(fb0 + i * 16) * 32]);                              \
      }                                                                       \
    }                                                                         \
  } while (0)

  // ---- Q fragments (loop-invariant, coalesced from frag-layout Qb) ----
  const int rb32 = rb * 4 + wave;
  bf16x8 qa[16];
#pragma unroll
  for (int kc = 0; kc < 16; ++kc)
    qa[kc] = *(const bf16x8*)(Qb + ((size_t)(rb32 * 16 + kc) * 64 + lane) * 8);

  // position B-fragment for this lane's qrow (col = lane&31 in S^T layout)
  const bf16x8 qp = *(const bf16x8*)(Qp + (size_t)(q0 + wrow + l31) * 16 +
                                     h5 * 8);

  f32x16 O[8];
#pragma unroll
  for (int ft = 0; ft < 8; ++ft)
#pragma unroll
    for (int r = 0; r < 16; ++r) O[ft][r] = 0.f;
  float lrow = 0.f;

  const int kswz = l31 & 7;
  const int vswz = (l31 >> 1) & 3;

  STAGE(0);

#pragma unroll 1
  for (int it = 0; it < ITERS; ++it) {
    const int cur = it & 1;
    asm volatile("s_waitcnt vmcnt(0)" ::: "memory");
    __syncthreads();

    const int nx = (it + 1 < ITERS) ? (it + 1) : (ITERS - 1);
    STAGE(nx);

    // ---- T = decay-exponent MFMA (issued first; latency hidden by S) ----
    f32x16 T;
#pragma unroll
    for (int r = 0; r < 16; ++r) T[r] = 0.f;
    {
      bf16x8 kpf = *(const bf16x8*)(&kpbuf[cur][l31 * 16 + h5 * 8]);
      T = mfma32(kpf, qp, T);
    }

    // ---- S^T = K Q^T : D[key][qrow], 32 keys x 32 rows ----
    f32x16 S;
#pragma unroll
    for (int r = 0; r < 16; ++r) S[r] = 0.f;
    __builtin_amdgcn_s_setprio(1);
#pragma unroll
    for (int kc = 0; kc < 16; ++kc) {
      bf16x8 kf = *(const bf16x8*)(&kbuf[cur][l31 * 256 +
                                   (((2 * kc + h5) ^ kswz) * 8)]);
      S = mfma32(kf, qa[kc], S);
    }
    __builtin_amdgcn_s_setprio(0);

    // ---- softmax: dec = exp2(-t*log2e + DECC); p = exp2(S*dec) ----
#pragma unroll
    for (int r = 0; r < 16; ++r) {
      float dec = exp2_hw(fmaf(T[r], -LOG2E, DECC));
      float p = exp2_hw(S[r] * dec);
      S[r] = p;
      lrow += p;
    }

    // ---- pack P to bf16 A-frags in-register (cvt_pk + permlane32_swap) ----
    uint32_t w0, w1, w2, w3, w4, w5, w6, w7;
    asm("v_cvt_pk_bf16_f32 %0, %1, %2" : "=v"(w0) : "v"(S[0]),  "v"(S[1]));
    asm("v_cvt_pk_bf16_f32 %0, %1, %2" : "=v"(w1) : "v"(S[2]),  "v"(S[3]));
    asm("v_cvt_pk_bf16_f32 %0, %1, %2" : "=v"(w2) : "v"(S[4]),  "v"(S[5]));
    asm("v_cvt_pk_bf16_f32 %0, %1, %2" : "=v"(w3) : "v"(S[6]),  "v"(S[7]));
    asm("v_cvt_pk_bf16_f32 %0, %1, %2" : "=v"(w4) : "v"(S[8]),  "v"(S[9]));
    asm("v_cvt_pk_bf16_f32 %0, %1, %2" : "=v"(w5) : "v"(S[10]), "v"(S[11]));
    asm("v_cvt_pk_bf16_f32 %0, %1, %2" : "=v"(w6) : "v"(S[12]), "v"(S[13]));
    asm("v_cvt_pk_bf16_f32 %0, %1, %2" : "=v"(w7) : "v"(S[14]), "v"(S[15]));
    asm volatile("v_permlane32_swap_b32 %0, %1" : "+v"(w2), "+v"(w0));
    asm volatile("v_permlane32_swap_b32 %0, %1" : "+v"(w3), "+v"(w1));
    asm volatile("v_permlane32_swap_b32 %0, %1" : "+v"(w6), "+v"(w4));
    asm volatile("v_permlane32_swap_b32 %0, %1" : "+v"(w7), "+v"(w5));
    PW pa0, pa1;
    pa0.u[0] = w0; pa0.u[1] = w1; pa0.u[2] = w2; pa0.u[3] = w3;  // keys 0..15
    pa1.u[0] = w4; pa1.u[1] = w5; pa1.u[2] = w6; pa1.u[3] = w7;  // keys 16..31

    // ---- O += P V (full 256 features, 8 ft-blocks of 32) ----
    __builtin_amdgcn_s_setprio(1);
#pragma unroll
    for (int kh = 0; kh < 2; ++kh) {
      const bf16x8 pa = kh ? pa1.v : pa0.v;
#pragma unroll
      for (int ft = 0; ft < 8; ++ft) {
        bf16x8 vf = *(const bf16x8*)(&vbuf[cur][(ft * 32 + l31) * 32 +
                                     (((2 * kh + h5) ^ vswz) * 8)]);
        O[ft] = mfma32(pa, vf, O[ft]);
      }
    }
    __builtin_amdgcn_s_setprio(0);
  }

  // ---- epilogue ----
  float lsum = lrow + __shfl_xor(lrow, 32);
#pragma unroll
  for (int ft = 0; ft < 8; ++ft)
#pragma unroll
    for (int r = 0; r < 16; ++r) {
      int row = q0 + wrow + (r & 3) + 8 * (r >> 2) + 4 * h5;
      Op[((size_t)sp * NTOK + row) * 256 + ft * 32 + l31] = f2bf(O[ft][r]);
    }
  if (lane < 32)
    ml[sp * NTOK + q0 + wrow + lane] = lsum;
#undef STAGE
}

// ---------------------------------------------------------------------------
// Kernel 3: combine splits: H = (sum O_s) / (1 + sum l_s) + residual.
// ---------------------------------------------------------------------------
__global__ __launch_bounds__(256) void combine_kernel(
    const float* __restrict__ X, const u16* __restrict__ Op,
    const float* __restrict__ ml, float* __restrict__ out) {
  const int row = blockIdx.x;
  const int f = threadIdx.x;
  float den = 1.f, num = 0.f;
#pragma unroll
  for (int s = 0; s < KSPLIT; ++s) {
    den += ml[s * NTOK + row];
    num += bf2f(Op[((size_t)s * NTOK + row) * 256 + f]);
  }
  out[(size_t)row * 256 + f] = num / den + X[(size_t)row * XSTRIDE + f];
}

// ---------------------------------------------------------------------------
extern "C" void kernel_launch(void* const* d_in, const int* in_sizes, int n_in,
                              void* d_out, int out_size, void* d_ws, size_t ws_size,
                              hipStream_t stream) {
  (void)in_sizes; (void)n_in; (void)out_size; (void)ws_size;
  const float* X  = (const float*)d_in[0];
  const float* WQ = (const float*)d_in[1];
  const float* bQ = (const float*)d_in[2];
  const float* WK = (const float*)d_in[3];
  const float* bK = (const float*)d_in[4];
  const float* WV = (const float*)d_in[5];
  const float* bV = (const float*)d_in[6];
  float* out = (float*)d_out;
  char* ws = (char*)d_ws;

  // ws: Qb 4M | Kb 4M | Vt 4M | Qp 256K | Kp 256K | Wt 384K | Op 32M | ml
  u16*   Qb = (u16*)(ws);
  u16*   Kb = (u16*)(ws + ((size_t)4 << 20));
  u16*   Vt = (u16*)(ws + ((size_t)8 << 20));
  u16*   Qp = (u16*)(ws + ((size_t)12 << 20));
  u16*   Kp = (u16*)(ws + ((size_t)12 << 20) + 262144);
  u16*   Wt = (u16*)(ws + ((size_t)12 << 20) + 524288);
  u16*   Op = (u16*)(ws + ((size_t)12 << 20) + 524288 + 393216);
  float* ml = (float*)(ws + ((size_t)12 << 20) + 524288 + 393216 +
                       (size_t)KSPLIT * NTOK * 256 * 2);

  pos_kernel<<<dim3(NTOK / 256), dim3(256), 0, stream>>>(X, Qp, Kp);
  wprep_kernel<<<dim3(768), dim3(256), 0, stream>>>(WQ, WK, WV, Wt);
  qkv_kernel<<<dim3(64, 12), dim3(256), 0, stream>>>(X, Wt, bQ, bK, bV,
                                                     Qb, Kb, Vt);
  attn_kernel<<<dim3(KSPLIT, NTOK / 128), dim3(256), 0, stream>>>(
      Qb, Kb, Vt, Qp, Kp, Op, ml);
  combine_kernel<<<dim3(NTOK), dim3(256), 0, stream>>>(X, Op, ml, out);
}

// Round 3
// 224.709 us; speedup vs baseline: 1.2797x; 1.2015x over previous
//
#include <hip/hip_runtime.h>
#include <hip/hip_bf16.h>
#include <stdint.h>

#define NTOK 8192
#define XSTRIDE 259
#define LOG2E 1.4426950408889634f
#define DECC (-3.4712336270551023f)   /* -4 + log2(log2 e) */
#define BN 32

typedef __bf16 bf16x8 __attribute__((ext_vector_type(8)));
typedef float f32x4 __attribute__((ext_vector_type(4)));
typedef float f32x16 __attribute__((ext_vector_type(16)));
typedef unsigned short u16;

union BF8 { u16 u[8]; bf16x8 v; };
union PW  { uint32_t u[4]; bf16x8 v; };

__device__ __forceinline__ u16 f2bf(float f) {
  uint32_t u = __float_as_uint(f);
  u += 0x7FFFu + ((u >> 16) & 1u);
  return (u16)(u >> 16);
}
__device__ __forceinline__ float bf2f(u16 h) {
  return __uint_as_float(((uint32_t)h) << 16);
}
__device__ __forceinline__ float exp2_hw(float x) {
  float r; asm("v_exp_f32 %0, %1" : "=v"(r) : "v"(x)); return r;
}
__device__ __forceinline__ f32x4 mfma16(bf16x8 a, bf16x8 b, f32x4 c) {
  return __builtin_amdgcn_mfma_f32_16x16x32_bf16(a, b, c, 0, 0, 0);
}
__device__ __forceinline__ f32x16 mfma32(bf16x8 a, bf16x8 b, f32x16 c) {
  return __builtin_amdgcn_mfma_f32_32x32x16_bf16(a, b, c, 0, 0, 0);
}
__device__ __forceinline__ void async16(const void* g, void* l) {
  __builtin_amdgcn_global_load_lds(
      (const __attribute__((address_space(1))) uint32_t*)g,
      (__attribute__((address_space(3))) uint32_t*)l, 16, 0, 0);
}
__device__ __forceinline__ void bsplit(float v, u16& h, u16& l) {
  h = f2bf(v);
  l = f2bf(v - bf2f(h));
}

// ---------------------------------------------------------------------------
// Kernel 0: position feature vectors for the MFMA-computed decay exponent.
//  t(q,k) = w_q + w_k - x_q x_k - y_q y_k - z_q z_k, 13-dim bf16 hi/lo dot.
// ---------------------------------------------------------------------------
__global__ __launch_bounds__(256) void pos_kernel(
    const float* __restrict__ X, u16* __restrict__ Qp, u16* __restrict__ Kp) {
  const int r = blockIdx.x * 256 + threadIdx.x;
  const float* xp = X + (size_t)r * XSTRIDE + 256;
  const float x = xp[0], y = xp[1], z = xp[2];
  const float w = 0.5f * (x * x + y * y + z * z);
  u16 xh, xl, yh, yl, zh, zl, wh, wl;
  bsplit(x, xh, xl); bsplit(y, yh, yl); bsplit(z, zh, zl); bsplit(w, wh, wl);
  const u16 one = 0x3F80u;
  const u16 SGN = 0x8000u;
  union { u16 u[16]; uint4 v4[2]; } uq, uk;
  uq.u[0] = wh;  uk.u[0] = one;
  uq.u[1] = wl;  uk.u[1] = one;
  uq.u[2] = one; uk.u[2] = wh;
  uq.u[3] = one; uk.u[3] = wl;
  uq.u[4] = (u16)(xh ^ SGN); uk.u[4] = xh;
  uq.u[5] = (u16)(xh ^ SGN); uk.u[5] = xl;
  uq.u[6] = (u16)(xl ^ SGN); uk.u[6] = xh;
  uq.u[7] = (u16)(yh ^ SGN); uk.u[7] = yh;
  uq.u[8] = (u16)(yh ^ SGN); uk.u[8] = yl;
  uq.u[9] = (u16)(yl ^ SGN); uk.u[9] = yh;
  uq.u[10] = (u16)(zh ^ SGN); uk.u[10] = zh;
  uq.u[11] = (u16)(zh ^ SGN); uk.u[11] = zl;
  uq.u[12] = (u16)(zl ^ SGN); uk.u[12] = zh;
  uq.u[13] = 0; uk.u[13] = 0;
  uq.u[14] = 0; uk.u[14] = 0;
  uq.u[15] = 0; uk.u[15] = 0;
  ((uint4*)Qp)[r * 2] = uq.v4[0];
  ((uint4*)Qp)[r * 2 + 1] = uq.v4[1];
  ((uint4*)Kp)[r * 2] = uk.v4[0];
  ((uint4*)Kp)[r * 2 + 1] = uk.v4[1];
}

// ---------------------------------------------------------------------------
// Kernel 0a: X -> bf16 once (removes 12x redundant f2bf + halves qkv reads).
// ---------------------------------------------------------------------------
__global__ __launch_bounds__(256) void xb_kernel(
    const float* __restrict__ X, u16* __restrict__ Xb) {
  const int t = threadIdx.x;
  const int row = blockIdx.x * 8 + (t >> 5);
  const int c0 = (t & 31) * 8;
  const float* xp = X + (size_t)row * XSTRIDE + c0;
  union { u16 u[8]; uint4 v; } o;
#pragma unroll
  for (int j = 0; j < 8; ++j) o.u[j] = f2bf(xp[j]);
  *(uint4*)(Xb + (size_t)row * 256 + c0) = o.v;
}

// ---------------------------------------------------------------------------
// Kernel 0b: W^T bf16 prep. Wt[o_global][k] = bf16(W[k][o]).
// ---------------------------------------------------------------------------
__global__ __launch_bounds__(256) void wprep_kernel(
    const float* __restrict__ WQ, const float* __restrict__ WK,
    const float* __restrict__ WV, u16* __restrict__ Wt) {
  const int o = blockIdx.x;          // 0..767
  const int which = o >> 8, oo = o & 255;
  const float* W = (which == 0) ? WQ : ((which == 1) ? WK : WV);
  const int k = threadIdx.x;
  Wt[(size_t)o * 256 + k] = f2bf(W[(size_t)k * 256 + oo]);
}

// ---------------------------------------------------------------------------
// Kernel 1: QKV projection.  grid (64 rowblocks, 12 col-chunks).
//  Reads pre-converted bf16 Xb. Q written in 32x32x16 B-fragment layout.
// ---------------------------------------------------------------------------
__global__ __launch_bounds__(256) void qkv_kernel(
    const u16* __restrict__ Xb, const u16* __restrict__ Wt,
    const float* __restrict__ bQ, const float* __restrict__ bK,
    const float* __restrict__ bV,
    u16* __restrict__ Qb, u16* __restrict__ Kb, u16* __restrict__ Vt) {
  __shared__ u16 wt[64 * 256];
  const int tid = threadIdx.x;
  const int lane = tid & 63;
  const int wave = tid >> 6;
  const int l15 = lane & 15;
  const int q4 = lane >> 4;
  const int rb = blockIdx.x;
  const int ch = blockIdx.y;
  const int which = ch >> 2;
  const int c0 = (ch & 3) * 64;
  const float* bias = (which == 0) ? bQ : ((which == 1) ? bK : bV);

  bf16x8 xa[2][8];
#pragma unroll
  for (int mt = 0; mt < 2; ++mt) {
    const int row = rb * 128 + wave * 32 + mt * 16 + l15;
#pragma unroll
    for (int kc = 0; kc < 8; ++kc)
      xa[mt][kc] = *(const bf16x8*)(Xb + (size_t)row * 256 + kc * 32 + q4 * 8);
  }
  {
    const u16* Wsrc = Wt + (size_t)(which * 256 + c0) * 256;
    const int rb0 = wave * 16;
#pragma unroll
    for (int i = 0; i < 8; ++i) {
      int r = rb0 + i * 2 + (lane >> 5);
      int c = (lane & 31) ^ (r & 7);
      async16(Wsrc + (size_t)r * 256 + c * 8, wt + (rb0 + i * 2) * 256);
    }
  }
  asm volatile("s_waitcnt vmcnt(0)" ::: "memory");
  __syncthreads();

  f32x4 acc[2][4];
#pragma unroll
  for (int mt = 0; mt < 2; ++mt)
#pragma unroll
    for (int nt = 0; nt < 4; ++nt) acc[mt][nt] = (f32x4){0.f, 0.f, 0.f, 0.f};

#pragma unroll
  for (int kc = 0; kc < 8; ++kc) {
#pragma unroll
    for (int nt = 0; nt < 4; ++nt) {
      bf16x8 wf = *(const bf16x8*)(wt + (nt * 16 + l15) * 256 +
                                   (((kc * 4 + q4) ^ (l15 & 7)) * 8));
#pragma unroll
      for (int mt = 0; mt < 2; ++mt)
        acc[mt][nt] = mfma16(xa[mt][kc], wf, acc[mt][nt]);
    }
  }
  float bc[4];
#pragma unroll
  for (int nt = 0; nt < 4; ++nt) bc[nt] = bias[c0 + nt * 16 + l15];

#pragma unroll
  for (int mt = 0; mt < 2; ++mt)
#pragma unroll
    for (int nt = 0; nt < 4; ++nt)
#pragma unroll
      for (int r = 0; r < 4; ++r) {
        float v = acc[mt][nt][r] + bc[nt];
        int grow = rb * 128 + wave * 32 + mt * 16 + q4 * 4 + r;
        int gc = c0 + nt * 16 + l15;
        if (which == 2)      Vt[(size_t)gc * NTOK + grow] = f2bf(v);
        else if (which == 1) Kb[(size_t)grow * 256 + gc] = f2bf(v);
        else                 Qb[(size_t)((grow >> 5) * 16 + (gc >> 4)) * 512 +
                                ((gc >> 3) & 1) * 256 + (grow & 31) * 8 +
                                (gc & 7)] = f2bf(v);
      }
}

// ---------------------------------------------------------------------------
// Kernel 2: flash attention, 32x32x16 MFMA, M=32 rows/wave, templated on
//  KSPLIT. KS=16: 8-wave blocks (256 q-rows) sharing one K/V tile -> same
//  66 KB LDS serves 16 waves/CU (4/SIMD, 2x the TLP) — attacks the measured
//  latency-bound signature (all busy counters low, Occupancy 22%).
//  KS=8: 4-wave blocks = exact prior configuration (workspace fallback).
// ---------------------------------------------------------------------------
template<int KS>
__global__ __launch_bounds__((KS == 16) ? 512 : 256, 2) void attn_kernel(
    const u16* __restrict__ Qb, const u16* __restrict__ Kb,
    const u16* __restrict__ Vt, const u16* __restrict__ Qp,
    const u16* __restrict__ Kp, u16* __restrict__ Op,
    float* __restrict__ ml) {
  constexpr int WPB = (KS == 16) ? 8 : 4;   // waves per block
  constexpr int KW  = WPB / 2;              // K-staging waves
  constexpr int SPL = NTOK / KS;            // keys per split
  constexpr int NIT = SPL / BN;             // tiles per split
  constexpr int IK  = BN / KW / 2;          // K stage iters (2 rows each)
  constexpr int FPW = 256 / KW;             // V features per staging wave
  constexpr int IV  = FPW / 16;             // V stage iters (16 feats each)

  __shared__ u16 kbuf[2][BN * 256];               // 16 KB x2  [key][256]
  __shared__ u16 vbuf[2][256 * BN];               // 16 KB x2  [feat][32]
  __shared__ u16 kpbuf[2][BN * 16];               // 1 KB x2   [key][16]

  const int tid = threadIdx.x;
  const int lane = tid & 63;
  const int wave = tid >> 6;
  const int l31 = lane & 31;
  const int h5 = lane >> 5;
  const int sp = blockIdx.x;
  const int rb = blockIdx.y;
  const int q0 = rb * (32 * WPB);
  const int wrow = wave * 32;

#define STAGE(T)                                                              \
  do {                                                                        \
    const int key0_ = sp * SPL + (T) * BN;                                    \
    const int b_ = (T) & 1;                                                   \
    if (wave < KW) {                                                          \
      const int rb0 = wave * (BN / KW);                                       \
      _Pragma("unroll")                                                       \
      for (int i = 0; i < IK; ++i) {                                          \
        int r = rb0 + i * 2 + (lane >> 5);                                    \
        int c = (lane & 31) ^ (r & 7);                                        \
        async16(Kb + (size_t)(key0_ + r) * 256 + c * 8,                       \
                &kbuf[b_][(rb0 + i * 2) * 256]);                              \
      }                                                                       \
      if (wave == 1)                                                          \
        async16(Kp + (size_t)(key0_ + (lane >> 1)) * 16 + (lane & 1) * 8,     \
                &kpbuf[b_][0]);                                               \
    } else {                                                                  \
      const int fb0 = (wave - KW) * FPW;                                      \
      _Pragma("unroll")                                                       \
      for (int i = 0; i < IV; ++i) {                                          \
        int f = fb0 + i * 16 + (lane >> 2);                                   \
        int c = (lane & 3) ^ ((f >> 1) & 3);                                  \
        async16(Vt + (size_t)f * NTOK + key0_ + c * 8,                        \
                &vbuf[b_][(fb0 + i * 16) * 32]);                              \
      }                                                                       \
    }                                                                         \
  } while (0)

  // ---- Q fragments (loop-invariant, coalesced from frag-layout Qb) ----
  const int rb32 = rb * WPB + wave;
  bf16x8 qa[16];
#pragma unroll
  for (int kc = 0; kc < 16; ++kc)
    qa[kc] = *(const bf16x8*)(Qb + ((size_t)(rb32 * 16 + kc) * 64 + lane) * 8);

  // position B-fragment for this lane's qrow (col = lane&31 in S^T layout)
  const bf16x8 qp = *(const bf16x8*)(Qp + (size_t)(q0 + wrow + l31) * 16 +
                                     h5 * 8);

  f32x16 O[8];
#pragma unroll
  for (int ft = 0; ft < 8; ++ft)
#pragma unroll
    for (int r = 0; r < 16; ++r) O[ft][r] = 0.f;
  float lrow = 0.f;

  const int kswz = l31 & 7;
  const int vswz = (l31 >> 1) & 3;

  STAGE(0);

#pragma unroll 1
  for (int it = 0; it < NIT; ++it) {
    const int cur = it & 1;
    asm volatile("s_waitcnt vmcnt(0)" ::: "memory");
    __syncthreads();

    const int nx = (it + 1 < NIT) ? (it + 1) : (NIT - 1);
    STAGE(nx);

    // ---- T = decay-exponent MFMA (issued first; latency hidden by S) ----
    f32x16 T;
#pragma unroll
    for (int r = 0; r < 16; ++r) T[r] = 0.f;
    {
      bf16x8 kpf = *(const bf16x8*)(&kpbuf[cur][l31 * 16 + h5 * 8]);
      T = mfma32(kpf, qp, T);
    }

    // ---- S^T = K Q^T : D[key][qrow], 32 keys x 32 rows ----
    f32x16 S;
#pragma unroll
    for (int r = 0; r < 16; ++r) S[r] = 0.f;
    __builtin_amdgcn_s_setprio(1);
#pragma unroll
    for (int kc = 0; kc < 16; ++kc) {
      bf16x8 kf = *(const bf16x8*)(&kbuf[cur][l31 * 256 +
                                   (((2 * kc + h5) ^ kswz) * 8)]);
      S = mfma32(kf, qa[kc], S);
    }
    __builtin_amdgcn_s_setprio(0);

    // ---- softmax: dec = exp2(-t*log2e + DECC); p = exp2(S*dec) ----
#pragma unroll
    for (int r = 0; r < 16; ++r) {
      float dec = exp2_hw(fmaf(T[r], -LOG2E, DECC));
      float p = exp2_hw(S[r] * dec);
      S[r] = p;
      lrow += p;
    }

    // ---- pack P to bf16 A-frags in-register (cvt_pk + permlane32_swap) ----
    uint32_t w0, w1, w2, w3, w4, w5, w6, w7;
    asm("v_cvt_pk_bf16_f32 %0, %1, %2" : "=v"(w0) : "v"(S[0]),  "v"(S[1]));
    asm("v_cvt_pk_bf16_f32 %0, %1, %2" : "=v"(w1) : "v"(S[2]),  "v"(S[3]));
    asm("v_cvt_pk_bf16_f32 %0, %1, %2" : "=v"(w2) : "v"(S[4]),  "v"(S[5]));
    asm("v_cvt_pk_bf16_f32 %0, %1, %2" : "=v"(w3) : "v"(S[6]),  "v"(S[7]));
    asm("v_cvt_pk_bf16_f32 %0, %1, %2" : "=v"(w4) : "v"(S[8]),  "v"(S[9]));
    asm("v_cvt_pk_bf16_f32 %0, %1, %2" : "=v"(w5) : "v"(S[10]), "v"(S[11]));
    asm("v_cvt_pk_bf16_f32 %0, %1, %2" : "=v"(w6) : "v"(S[12]), "v"(S[13]));
    asm("v_cvt_pk_bf16_f32 %0, %1, %2" : "=v"(w7) : "v"(S[14]), "v"(S[15]));
    asm volatile("v_permlane32_swap_b32 %0, %1" : "+v"(w2), "+v"(w0));
    asm volatile("v_permlane32_swap_b32 %0, %1" : "+v"(w3), "+v"(w1));
    asm volatile("v_permlane32_swap_b32 %0, %1" : "+v"(w6), "+v"(w4));
    asm volatile("v_permlane32_swap_b32 %0, %1" : "+v"(w7), "+v"(w5));
    PW pa0, pa1;
    pa0.u[0] = w0; pa0.u[1] = w1; pa0.u[2] = w2; pa0.u[3] = w3;  // keys 0..15
    pa1.u[0] = w4; pa1.u[1] = w5; pa1.u[2] = w6; pa1.u[3] = w7;  // keys 16..31

    // ---- O += P V (full 256 features, 8 ft-blocks of 32) ----
    __builtin_amdgcn_s_setprio(1);
#pragma unroll
    for (int kh = 0; kh < 2; ++kh) {
      const bf16x8 pa = kh ? pa1.v : pa0.v;
#pragma unroll
      for (int ft = 0; ft < 8; ++ft) {
        bf16x8 vf = *(const bf16x8*)(&vbuf[cur][(ft * 32 + l31) * 32 +
                                     (((2 * kh + h5) ^ vswz) * 8)]);
        O[ft] = mfma32(pa, vf, O[ft]);
      }
    }
    __builtin_amdgcn_s_setprio(0);
  }

  // ---- epilogue ----
  float lsum = lrow + __shfl_xor(lrow, 32);
#pragma unroll
  for (int ft = 0; ft < 8; ++ft)
#pragma unroll
    for (int r = 0; r < 16; ++r) {
      int row = q0 + wrow + (r & 3) + 8 * (r >> 2) + 4 * h5;
      Op[((size_t)sp * NTOK + row) * 256 + ft * 32 + l31] = f2bf(O[ft][r]);
    }
  if (lane < 32)
    ml[sp * NTOK + q0 + wrow + lane] = lsum;
#undef STAGE
}

// ---------------------------------------------------------------------------
// Kernel 3: combine splits: H = (sum O_s) / (1 + sum l_s) + residual.
// ---------------------------------------------------------------------------
template<int KS>
__global__ __launch_bounds__(256) void combine_kernel(
    const float* __restrict__ X, const u16* __restrict__ Op,
    const float* __restrict__ ml, float* __restrict__ out) {
  const int row = blockIdx.x;
  const int f = threadIdx.x;
  float den = 1.f, num = 0.f;
#pragma unroll
  for (int s = 0; s < KS; ++s) {
    den += ml[s * NTOK + row];
    num += bf2f(Op[((size_t)s * NTOK + row) * 256 + f]);
  }
  out[(size_t)row * 256 + f] = num / den + X[(size_t)row * XSTRIDE + f];
}

// ---------------------------------------------------------------------------
extern "C" void kernel_launch(void* const* d_in, const int* in_sizes, int n_in,
                              void* d_out, int out_size, void* d_ws, size_t ws_size,
                              hipStream_t stream) {
  (void)in_sizes; (void)n_in; (void)out_size;
  const float* X  = (const float*)d_in[0];
  const float* WQ = (const float*)d_in[1];
  const float* bQ = (const float*)d_in[2];
  const float* WK = (const float*)d_in[3];
  const float* bK = (const float*)d_in[4];
  const float* WV = (const float*)d_in[5];
  const float* bV = (const float*)d_in[6];
  float* out = (float*)d_out;
  char* ws = (char*)d_ws;

  // ws: Qb 4M | Kb 4M | Vt 4M | Qp 256K | Kp 256K | Wt 384K | Xb 4M |
  //     ml 512K (reserved) | Op KS*4M
  u16*   Qb = (u16*)(ws);
  u16*   Kb = (u16*)(ws + ((size_t)4 << 20));
  u16*   Vt = (u16*)(ws + ((size_t)8 << 20));
  u16*   Qp = (u16*)(ws + ((size_t)12 << 20));
  u16*   Kp = (u16*)(ws + ((size_t)12 << 20) + 262144);
  u16*   Wt = (u16*)(ws + ((size_t)12 << 20) + 524288);
  u16*   Xb = (u16*)(ws + ((size_t)12 << 20) + 524288 + 393216);
  float* ml = (float*)(ws + ((size_t)16 << 20) + 524288 + 393216);
  u16*   Op = (u16*)(ws + ((size_t)16 << 20) + 524288 + 393216 + 524288);

  const size_t op_off = ((size_t)16 << 20) + 524288 + 393216 + 524288;
  const size_t need16 = op_off + (size_t)16 * NTOK * 256 * 2;
  const bool big = (ws_size >= need16);

  pos_kernel<<<dim3(NTOK / 256), dim3(256), 0, stream>>>(X, Qp, Kp);
  xb_kernel<<<dim3(NTOK / 8), dim3(256), 0, stream>>>(X, Xb);
  wprep_kernel<<<dim3(768), dim3(256), 0, stream>>>(WQ, WK, WV, Wt);
  qkv_kernel<<<dim3(64, 12), dim3(256), 0, stream>>>(Xb, Wt, bQ, bK, bV,
                                                     Qb, Kb, Vt);
  if (big) {
    attn_kernel<16><<<dim3(16, NTOK / 256), dim3(512), 0, stream>>>(
        Qb, Kb, Vt, Qp, Kp, Op, ml);
    combine_kernel<16><<<dim3(NTOK), dim3(256), 0, stream>>>(X, Op, ml, out);
  } else {
    attn_kernel<8><<<dim3(8, NTOK / 128), dim3(256), 0, stream>>>(
        Qb, Kb, Vt, Qp, Kp, Op, ml);
    combine_kernel<8><<<dim3(NTOK), dim3(256), 0, stream>>>(X, Op, ml, out);
  }
}

// Round 4
// 218.273 us; speedup vs baseline: 1.3175x; 1.0295x over previous
//
#include <hip/hip_runtime.h>
#include <hip/hip_bf16.h>
#include <stdint.h>

#define NTOK 8192
#define XSTRIDE 259
#define LOG2E 1.4426950408889634f
#define DECC (-3.4712336270551023f)   /* -4 + log2(log2 e) */
#define KSPLIT 8
#define SPLEN (NTOK / KSPLIT)   /* 1024 */
#define BN 32
#define ITERS (SPLEN / BN)      /* 32 */

typedef __bf16 bf16x8 __attribute__((ext_vector_type(8)));
typedef float f32x4 __attribute__((ext_vector_type(4)));
typedef unsigned short u16;

union BF8 { u16 u[8]; bf16x8 v; };
union PW  { uint32_t u[4]; bf16x8 v; };

__device__ __forceinline__ u16 f2bf(float f) {
  uint32_t u = __float_as_uint(f);
  u += 0x7FFFu + ((u >> 16) & 1u);
  return (u16)(u >> 16);
}
__device__ __forceinline__ float bf2f(u16 h) {
  return __uint_as_float(((uint32_t)h) << 16);
}
__device__ __forceinline__ float exp2_hw(float x) {
  float r; asm("v_exp_f32 %0, %1" : "=v"(r) : "v"(x)); return r;
}
__device__ __forceinline__ f32x4 mfma16(bf16x8 a, bf16x8 b, f32x4 c) {
  return __builtin_amdgcn_mfma_f32_16x16x32_bf16(a, b, c, 0, 0, 0);
}
__device__ __forceinline__ void async16(const void* g, void* l) {
  __builtin_amdgcn_global_load_lds(
      (const __attribute__((address_space(1))) uint32_t*)g,
      (__attribute__((address_space(3))) uint32_t*)l, 16, 0, 0);
}
__device__ __forceinline__ void bsplit(float v, u16& h, u16& l) {
  h = f2bf(v);
  l = f2bf(v - bf2f(h));
}

// ---------------------------------------------------------------------------
// Kernel 0: position feature vectors for the MFMA-computed decay exponent.
//  t(q,k) = w_q + w_k - x_q x_k - y_q y_k - z_q z_k, 13-dim bf16 hi/lo dot.
// ---------------------------------------------------------------------------
__global__ __launch_bounds__(256) void pos_kernel(
    const float* __restrict__ X, u16* __restrict__ Qp, u16* __restrict__ Kp) {
  const int r = blockIdx.x * 256 + threadIdx.x;
  const float* xp = X + (size_t)r * XSTRIDE + 256;
  const float x = xp[0], y = xp[1], z = xp[2];
  const float w = 0.5f * (x * x + y * y + z * z);
  u16 xh, xl, yh, yl, zh, zl, wh, wl;
  bsplit(x, xh, xl); bsplit(y, yh, yl); bsplit(z, zh, zl); bsplit(w, wh, wl);
  const u16 one = 0x3F80u;
  const u16 SGN = 0x8000u;
  union { u16 u[16]; uint4 v4[2]; } uq, uk;
  uq.u[0] = wh;  uk.u[0] = one;
  uq.u[1] = wl;  uk.u[1] = one;
  uq.u[2] = one; uk.u[2] = wh;
  uq.u[3] = one; uk.u[3] = wl;
  uq.u[4] = (u16)(xh ^ SGN); uk.u[4] = xh;
  uq.u[5] = (u16)(xh ^ SGN); uk.u[5] = xl;
  uq.u[6] = (u16)(xl ^ SGN); uk.u[6] = xh;
  uq.u[7] = (u16)(yh ^ SGN); uk.u[7] = yh;
  uq.u[8] = (u16)(yh ^ SGN); uk.u[8] = yl;
  uq.u[9] = (u16)(yl ^ SGN); uk.u[9] = yh;
  uq.u[10] = (u16)(zh ^ SGN); uk.u[10] = zh;
  uq.u[11] = (u16)(zh ^ SGN); uk.u[11] = zl;
  uq.u[12] = (u16)(zl ^ SGN); uk.u[12] = zh;
  uq.u[13] = 0; uk.u[13] = 0;
  uq.u[14] = 0; uk.u[14] = 0;
  uq.u[15] = 0; uk.u[15] = 0;
  ((uint4*)Qp)[r * 2] = uq.v4[0];
  ((uint4*)Qp)[r * 2 + 1] = uq.v4[1];
  ((uint4*)Kp)[r * 2] = uk.v4[0];
  ((uint4*)Kp)[r * 2 + 1] = uk.v4[1];
}

// ---------------------------------------------------------------------------
// Kernel 0a: X -> bf16 once.
// ---------------------------------------------------------------------------
__global__ __launch_bounds__(256) void xb_kernel(
    const float* __restrict__ X, u16* __restrict__ Xb) {
  const int t = threadIdx.x;
  const int row = blockIdx.x * 8 + (t >> 5);
  const int c0 = (t & 31) * 8;
  const float* xp = X + (size_t)row * XSTRIDE + c0;
  union { u16 u[8]; uint4 v; } o;
#pragma unroll
  for (int j = 0; j < 8; ++j) o.u[j] = f2bf(xp[j]);
  *(uint4*)(Xb + (size_t)row * 256 + c0) = o.v;
}

// ---------------------------------------------------------------------------
// Kernel 0b: W^T bf16 prep. Wt[o_global][k] = bf16(W[k][o]).
// ---------------------------------------------------------------------------
__global__ __launch_bounds__(256) void wprep_kernel(
    const float* __restrict__ WQ, const float* __restrict__ WK,
    const float* __restrict__ WV, u16* __restrict__ Wt) {
  const int o = blockIdx.x;          // 0..767
  const int which = o >> 8, oo = o & 255;
  const float* W = (which == 0) ? WQ : ((which == 1) ? WK : WV);
  const int k = threadIdx.x;
  Wt[(size_t)o * 256 + k] = f2bf(W[(size_t)k * 256 + oo]);
}

// ---------------------------------------------------------------------------
// Kernel 1: QKV projection. Qb back to plain row-major [row][256] (M=16 attn
// reads its B-frags directly from row-major).
// ---------------------------------------------------------------------------
__global__ __launch_bounds__(256) void qkv_kernel(
    const u16* __restrict__ Xb, const u16* __restrict__ Wt,
    const float* __restrict__ bQ, const float* __restrict__ bK,
    const float* __restrict__ bV,
    u16* __restrict__ Qb, u16* __restrict__ Kb, u16* __restrict__ Vt) {
  __shared__ u16 wt[64 * 256];
  const int tid = threadIdx.x;
  const int lane = tid & 63;
  const int wave = tid >> 6;
  const int l15 = lane & 15;
  const int q4 = lane >> 4;
  const int rb = blockIdx.x;
  const int ch = blockIdx.y;
  const int which = ch >> 2;
  const int c0 = (ch & 3) * 64;
  const float* bias = (which == 0) ? bQ : ((which == 1) ? bK : bV);

  bf16x8 xa[2][8];
#pragma unroll
  for (int mt = 0; mt < 2; ++mt) {
    const int row = rb * 128 + wave * 32 + mt * 16 + l15;
#pragma unroll
    for (int kc = 0; kc < 8; ++kc)
      xa[mt][kc] = *(const bf16x8*)(Xb + (size_t)row * 256 + kc * 32 + q4 * 8);
  }
  {
    const u16* Wsrc = Wt + (size_t)(which * 256 + c0) * 256;
    const int rb0 = wave * 16;
#pragma unroll
    for (int i = 0; i < 8; ++i) {
      int r = rb0 + i * 2 + (lane >> 5);
      int c = (lane & 31) ^ (r & 7);
      async16(Wsrc + (size_t)r * 256 + c * 8, wt + (rb0 + i * 2) * 256);
    }
  }
  asm volatile("s_waitcnt vmcnt(0)" ::: "memory");
  __syncthreads();

  f32x4 acc[2][4];
#pragma unroll
  for (int mt = 0; mt < 2; ++mt)
#pragma unroll
    for (int nt = 0; nt < 4; ++nt) acc[mt][nt] = (f32x4){0.f, 0.f, 0.f, 0.f};

#pragma unroll
  for (int kc = 0; kc < 8; ++kc) {
#pragma unroll
    for (int nt = 0; nt < 4; ++nt) {
      bf16x8 wf = *(const bf16x8*)(wt + (nt * 16 + l15) * 256 +
                                   (((kc * 4 + q4) ^ (l15 & 7)) * 8));
#pragma unroll
      for (int mt = 0; mt < 2; ++mt)
        acc[mt][nt] = mfma16(xa[mt][kc], wf, acc[mt][nt]);
    }
  }
  float bc[4];
#pragma unroll
  for (int nt = 0; nt < 4; ++nt) bc[nt] = bias[c0 + nt * 16 + l15];

#pragma unroll
  for (int mt = 0; mt < 2; ++mt)
#pragma unroll
    for (int nt = 0; nt < 4; ++nt)
#pragma unroll
      for (int r = 0; r < 4; ++r) {
        float v = acc[mt][nt][r] + bc[nt];
        int grow = rb * 128 + wave * 32 + mt * 16 + q4 * 4 + r;
        int gc = c0 + nt * 16 + l15;
        if (which == 2)      Vt[(size_t)gc * NTOK + grow] = f2bf(v);
        else if (which == 1) Kb[(size_t)grow * 256 + gc] = f2bf(v);
        else                 Qb[(size_t)grow * 256 + gc] = f2bf(v);
      }
}

// ---------------------------------------------------------------------------
// Kernel 2: flash attention, M=16, 16x16x32 MFMA — the R0-proven structure
//  with the session's validated upgrades, restructured for 3 waves/SIMD:
//   * launch_bounds(256,3): regs <= 170/wave -> 12 waves/CU (was 8, reg-capped
//     at 256 by O[128]+qa[64] in the M=32 variants; occupancy never moved).
//   * LDS 50KB/block (dbuf K 32K + SINGLE-buffer V 16K + kp 2K) -> 3 blk/CU.
//     V(it) staged at iter start, waited by counted vmcnt(4) + raw s_barrier
//     (K(it+1) stays in flight across the barrier — no full drain).
//   * swapped S = mfma(K,Q) with KEY-PERMUTED kbuf: row r holds key sigma(r),
//     sigma(nt*16+q4*4+rr) = q4*8+nt*4+rr (bijection). Lane then holds P for
//     qrow=l15, keys q4*8..q4*8+7 == exactly the PV A-frag -> pack is 4
//     cvt_pk, zero cross-lane ops, zero pbuf/fences. kp permuted identically;
//     vbuf stays identity order.
//   * decay exponent via 2 padded MFMAs (T), softmax = 5 VALU/score.
// ---------------------------------------------------------------------------
__global__ __launch_bounds__(256, 3) void attn_kernel(
    const u16* __restrict__ Qb, const u16* __restrict__ Kb,
    const u16* __restrict__ Vt, const u16* __restrict__ Qp,
    const u16* __restrict__ Kp, u16* __restrict__ Op,
    float* __restrict__ ml) {
  __shared__ u16 kpbuf[2][BN * 16];     // 2 KB  (before kbuf: pad-read safe)
  __shared__ u16 kbuf[2][BN * 256];     // 32 KB  [row][256], row=key sigma(r)
  __shared__ u16 vbuf[256 * BN];        // 16 KB  [feat][32], identity keys

  const int tid = threadIdx.x;
  const int lane = tid & 63;
  const int wave = tid >> 6;
  const int l15 = lane & 15;
  const int q4 = lane >> 4;
  const int sp = blockIdx.x;
  const int rb = blockIdx.y;
  const int q0 = rb * 64;
  const int wrow = wave * 16;

  // sigma(r): key permutation for kbuf/kpbuf rows
#define SIG(r) ((((r) >> 2) & 3) * 8 + ((r) >> 4) * 4 + ((r) & 3))

#define STAGE_K(T)                                                            \
  do {                                                                        \
    const int key0_ = sp * SPLEN + (T) * BN;                                  \
    const int b_ = (T) & 1;                                                   \
    _Pragma("unroll")                                                         \
    for (int i = 0; i < 4; ++i) {                                             \
      int r = wave * 8 + i * 2 + (lane >> 5);                                 \
      int c = (lane & 31) ^ (r & 7);                                          \
      async16(Kb + (size_t)(key0_ + SIG(r)) * 256 + c * 8,                    \
              &kbuf[b_][(wave * 8 + i * 2) * 256]);                           \
    }                                                                         \
    if (wave == 0)                                                            \
      async16(Kp + (size_t)(key0_ + SIG(lane >> 1)) * 16 + (lane & 1) * 8,    \
              &kpbuf[b_][0]);                                                 \
  } while (0)

#define STAGE_V(T)                                                            \
  do {                                                                        \
    const int key0_ = sp * SPLEN + (T) * BN;                                  \
    _Pragma("unroll")                                                         \
    for (int i = 0; i < 4; ++i) {                                             \
      int f = (wave * 4 + i) * 16 + (lane >> 2);                              \
      int c = (lane & 3) ^ (f & 3);                                           \
      async16(Vt + (size_t)f * NTOK + key0_ + c * 8,                          \
              &vbuf[(wave * 4 + i) * 16 * 32]);                               \
    }                                                                         \
  } while (0)

  // ---- loop-invariant registers ----
  bf16x8 qa[8];                              // Q B-frags (col=l15=qrow)
#pragma unroll
  for (int kc = 0; kc < 8; ++kc)
    qa[kc] = *(const bf16x8*)(Qb + (size_t)(q0 + wrow + l15) * 256 +
                              kc * 32 + q4 * 8);
  bf16x8 qp;                                 // position B-frag, zero for q4>=2
  {
    PW z;
    if (q4 < 2) {
      z.v = *(const bf16x8*)(Qp + (size_t)(q0 + wrow + l15) * 16 + q4 * 8);
    } else {
      z.u[0] = 0; z.u[1] = 0; z.u[2] = 0; z.u[3] = 0;
    }
    qp = z.v;
  }

  f32x4 O[16];
#pragma unroll
  for (int ft = 0; ft < 16; ++ft) O[ft] = (f32x4){0.f, 0.f, 0.f, 0.f};
  float lrow = 0.f;

  STAGE_K(0);
  asm volatile("s_waitcnt vmcnt(0)" ::: "memory");
  __builtin_amdgcn_s_barrier();

#pragma unroll 1
  for (int it = 0; it < ITERS; ++it) {
    const int cur = it & 1;
    const int nx = (it + 1 < ITERS) ? (it + 1) : it;  // last: benign rewrite

    STAGE_V(it);
    STAGE_K(nx);

    // ---- T = decay-exponent MFMAs (kp rows permuted like kbuf) ----
    f32x4 T[2], S[2];
#pragma unroll
    for (int nt = 0; nt < 2; ++nt) {
      bf16x8 kpf = *(const bf16x8*)(&kpbuf[cur][(nt * 16 + l15) * 16 + q4 * 8]);
      T[nt] = mfma16(kpf, qp, (f32x4){0.f, 0.f, 0.f, 0.f});
      S[nt] = (f32x4){0.f, 0.f, 0.f, 0.f};
    }

    // ---- S^T = K Q^T (D: col=l15=qrow, row=q4*4+r=key-slot) ----
    __builtin_amdgcn_s_setprio(1);
#pragma unroll
    for (int kc = 0; kc < 8; ++kc) {
#pragma unroll
      for (int nt = 0; nt < 2; ++nt) {
        bf16x8 kf = *(const bf16x8*)(&kbuf[cur][(nt * 16 + l15) * 256 +
                                     (((kc * 4 + q4) ^ (l15 & 7)) * 8)]);
        S[nt] = mfma16(kf, qa[kc], S[nt]);
      }
    }
    __builtin_amdgcn_s_setprio(0);

    // ---- softmax: dec = exp2(-t*log2e + DECC); p = exp2(S*dec) ----
#pragma unroll
    for (int nt = 0; nt < 2; ++nt)
#pragma unroll
      for (int r = 0; r < 4; ++r) {
        float dec = exp2_hw(fmaf(T[nt][r], -LOG2E, DECC));
        float p = exp2_hw(S[nt][r] * dec);
        S[nt][r] = p;
        lrow += p;
      }

    // ---- pack P A-frag in-register: keys q4*8+j, j = nt*4+r (sigma) ----
    PW pw;
    asm("v_cvt_pk_bf16_f32 %0, %1, %2" : "=v"(pw.u[0]) : "v"(S[0][0]), "v"(S[0][1]));
    asm("v_cvt_pk_bf16_f32 %0, %1, %2" : "=v"(pw.u[1]) : "v"(S[0][2]), "v"(S[0][3]));
    asm("v_cvt_pk_bf16_f32 %0, %1, %2" : "=v"(pw.u[2]) : "v"(S[1][0]), "v"(S[1][1]));
    asm("v_cvt_pk_bf16_f32 %0, %1, %2" : "=v"(pw.u[3]) : "v"(S[1][2]), "v"(S[1][3]));
    const bf16x8 pa = pw.v;

    // ---- wait own V loads (K(nx) stays in flight), all-wave barrier ----
    if (wave == 0) {
      asm volatile("s_waitcnt vmcnt(5)" ::: "memory");   // 4 K + 1 kp pending
    } else {
      asm volatile("s_waitcnt vmcnt(4)" ::: "memory");   // 4 K pending
    }
    __builtin_amdgcn_s_barrier();

    // ---- O += P V (identity key order in vbuf) ----
    __builtin_amdgcn_s_setprio(1);
#pragma unroll
    for (int ft = 0; ft < 16; ++ft) {
      bf16x8 vf = *(const bf16x8*)(&vbuf[(ft * 16 + l15) * 32 +
                                   ((q4 ^ (l15 & 3)) * 8)]);
      O[ft] = mfma16(pa, vf, O[ft]);
    }
    __builtin_amdgcn_s_setprio(0);

    // ---- drain K(nx); barrier frees vbuf + publishes kbuf[nx] ----
    asm volatile("s_waitcnt vmcnt(0)" ::: "memory");
    __builtin_amdgcn_s_barrier();
  }

  // ---- epilogue ----
  float lsum = lrow + __shfl_xor(lrow, 16);
  lsum += __shfl_xor(lsum, 32);
#pragma unroll
  for (int ft = 0; ft < 16; ++ft)
#pragma unroll
    for (int r = 0; r < 4; ++r) {
      int row = q0 + wrow + q4 * 4 + r;
      Op[((size_t)sp * NTOK + row) * 256 + ft * 16 + l15] = f2bf(O[ft][r]);
    }
  if (lane < 16)
    ml[sp * NTOK + q0 + wrow + l15] = lsum;
#undef STAGE_K
#undef STAGE_V
#undef SIG
}

// ---------------------------------------------------------------------------
// Kernel 3: combine splits: H = (sum O_s) / (1 + sum l_s) + residual.
// ---------------------------------------------------------------------------
__global__ __launch_bounds__(256) void combine_kernel(
    const float* __restrict__ X, const u16* __restrict__ Op,
    const float* __restrict__ ml, float* __restrict__ out) {
  const int row = blockIdx.x;
  const int f = threadIdx.x;
  float den = 1.f, num = 0.f;
#pragma unroll
  for (int s = 0; s < KSPLIT; ++s) {
    den += ml[s * NTOK + row];
    num += bf2f(Op[((size_t)s * NTOK + row) * 256 + f]);
  }
  out[(size_t)row * 256 + f] = num / den + X[(size_t)row * XSTRIDE + f];
}

// ---------------------------------------------------------------------------
extern "C" void kernel_launch(void* const* d_in, const int* in_sizes, int n_in,
                              void* d_out, int out_size, void* d_ws, size_t ws_size,
                              hipStream_t stream) {
  (void)in_sizes; (void)n_in; (void)out_size; (void)ws_size;
  const float* X  = (const float*)d_in[0];
  const float* WQ = (const float*)d_in[1];
  const float* bQ = (const float*)d_in[2];
  const float* WK = (const float*)d_in[3];
  const float* bK = (const float*)d_in[4];
  const float* WV = (const float*)d_in[5];
  const float* bV = (const float*)d_in[6];
  float* out = (float*)d_out;
  char* ws = (char*)d_ws;

  // ws: Qb 4M | Kb 4M | Vt 4M | Qp 256K | Kp 256K | Wt 384K | Xb 4M |
  //     ml 512K | Op 32M   (~49.5 MB total; R3 proved ws >= 82 MB)
  u16*   Qb = (u16*)(ws);
  u16*   Kb = (u16*)(ws + ((size_t)4 << 20));
  u16*   Vt = (u16*)(ws + ((size_t)8 << 20));
  u16*   Qp = (u16*)(ws + ((size_t)12 << 20));
  u16*   Kp = (u16*)(ws + ((size_t)12 << 20) + 262144);
  u16*   Wt = (u16*)(ws + ((size_t)12 << 20) + 524288);
  u16*   Xb = (u16*)(ws + ((size_t)12 << 20) + 524288 + 393216);
  float* ml = (float*)(ws + ((size_t)16 << 20) + 524288 + 393216);
  u16*   Op = (u16*)(ws + ((size_t)16 << 20) + 524288 + 393216 + 524288);

  pos_kernel<<<dim3(NTOK / 256), dim3(256), 0, stream>>>(X, Qp, Kp);
  xb_kernel<<<dim3(NTOK / 8), dim3(256), 0, stream>>>(X, Xb);
  wprep_kernel<<<dim3(768), dim3(256), 0, stream>>>(WQ, WK, WV, Wt);
  qkv_kernel<<<dim3(64, 12), dim3(256), 0, stream>>>(Xb, Wt, bQ, bK, bV,
                                                     Qb, Kb, Vt);
  attn_kernel<<<dim3(KSPLIT, NTOK / 64), dim3(256), 0, stream>>>(
      Qb, Kb, Vt, Qp, Kp, Op, ml);
  combine_kernel<<<dim3(NTOK), dim3(256), 0, stream>>>(X, Op, ml, out);
}

// Round 5
// 208.708 us; speedup vs baseline: 1.3779x; 1.0458x over previous
//
#include <hip/hip_runtime.h>
#include <hip/hip_bf16.h>
#include <stdint.h>

#define NTOK 8192
#define XSTRIDE 259
#define LOG2E 1.4426950408889634f
#define DECC (-3.4712336270551023f)   /* -4 + log2(log2 e) */
#define KSPLIT 8
#define SPLEN (NTOK / KSPLIT)   /* 1024 */
#define BN 32
#define ITERS (SPLEN / BN)      /* 32 */

typedef __bf16 bf16x8 __attribute__((ext_vector_type(8)));
typedef float f32x4 __attribute__((ext_vector_type(4)));
typedef float f32x16 __attribute__((ext_vector_type(16)));
typedef unsigned short u16;

union BF8 { u16 u[8]; bf16x8 v; };
union PW  { uint32_t u[4]; bf16x8 v; };

__device__ __forceinline__ u16 f2bf(float f) {
  uint32_t u = __float_as_uint(f);
  u += 0x7FFFu + ((u >> 16) & 1u);
  return (u16)(u >> 16);
}
__device__ __forceinline__ float bf2f(u16 h) {
  return __uint_as_float(((uint32_t)h) << 16);
}
__device__ __forceinline__ float exp2_hw(float x) {
  float r; asm("v_exp_f32 %0, %1" : "=v"(r) : "v"(x)); return r;
}
__device__ __forceinline__ f32x4 mfma16(bf16x8 a, bf16x8 b, f32x4 c) {
  return __builtin_amdgcn_mfma_f32_16x16x32_bf16(a, b, c, 0, 0, 0);
}
__device__ __forceinline__ f32x16 mfma32(bf16x8 a, bf16x8 b, f32x16 c) {
  return __builtin_amdgcn_mfma_f32_32x32x16_bf16(a, b, c, 0, 0, 0);
}
__device__ __forceinline__ void async16(const void* g, void* l) {
  __builtin_amdgcn_global_load_lds(
      (const __attribute__((address_space(1))) uint32_t*)g,
      (__attribute__((address_space(3))) uint32_t*)l, 16, 0, 0);
}
__device__ __forceinline__ void bsplit(float v, u16& h, u16& l) {
  h = f2bf(v);
  l = f2bf(v - bf2f(h));
}

// ---------------------------------------------------------------------------
// Kernel 0: position feature vectors for the MFMA-computed decay exponent.
//  t(q,k) = w_q + w_k - x_q x_k - y_q y_k - z_q z_k, 13-dim bf16 hi/lo dot.
// ---------------------------------------------------------------------------
__global__ __launch_bounds__(256) void pos_kernel(
    const float* __restrict__ X, u16* __restrict__ Qp, u16* __restrict__ Kp) {
  const int r = blockIdx.x * 256 + threadIdx.x;
  const float* xp = X + (size_t)r * XSTRIDE + 256;
  const float x = xp[0], y = xp[1], z = xp[2];
  const float w = 0.5f * (x * x + y * y + z * z);
  u16 xh, xl, yh, yl, zh, zl, wh, wl;
  bsplit(x, xh, xl); bsplit(y, yh, yl); bsplit(z, zh, zl); bsplit(w, wh, wl);
  const u16 one = 0x3F80u;
  const u16 SGN = 0x8000u;
  union { u16 u[16]; uint4 v4[2]; } uq, uk;
  uq.u[0] = wh;  uk.u[0] = one;
  uq.u[1] = wl;  uk.u[1] = one;
  uq.u[2] = one; uk.u[2] = wh;
  uq.u[3] = one; uk.u[3] = wl;
  uq.u[4] = (u16)(xh ^ SGN); uk.u[4] = xh;
  uq.u[5] = (u16)(xh ^ SGN); uk.u[5] = xl;
  uq.u[6] = (u16)(xl ^ SGN); uk.u[6] = xh;
  uq.u[7] = (u16)(yh ^ SGN); uk.u[7] = yh;
  uq.u[8] = (u16)(yh ^ SGN); uk.u[8] = yl;
  uq.u[9] = (u16)(yl ^ SGN); uk.u[9] = yh;
  uq.u[10] = (u16)(zh ^ SGN); uk.u[10] = zh;
  uq.u[11] = (u16)(zh ^ SGN); uk.u[11] = zl;
  uq.u[12] = (u16)(zl ^ SGN); uk.u[12] = zh;
  uq.u[13] = 0; uk.u[13] = 0;
  uq.u[14] = 0; uk.u[14] = 0;
  uq.u[15] = 0; uk.u[15] = 0;
  ((uint4*)Qp)[r * 2] = uq.v4[0];
  ((uint4*)Qp)[r * 2 + 1] = uq.v4[1];
  ((uint4*)Kp)[r * 2] = uk.v4[0];
  ((uint4*)Kp)[r * 2 + 1] = uk.v4[1];
}

// ---------------------------------------------------------------------------
// Kernel 0a: X -> bf16 once.
// ---------------------------------------------------------------------------
__global__ __launch_bounds__(256) void xb_kernel(
    const float* __restrict__ X, u16* __restrict__ Xb) {
  const int t = threadIdx.x;
  const int row = blockIdx.x * 8 + (t >> 5);
  const int c0 = (t & 31) * 8;
  const float* xp = X + (size_t)row * XSTRIDE + c0;
  union { u16 u[8]; uint4 v; } o;
#pragma unroll
  for (int j = 0; j < 8; ++j) o.u[j] = f2bf(xp[j]);
  *(uint4*)(Xb + (size_t)row * 256 + c0) = o.v;
}

// ---------------------------------------------------------------------------
// Kernel 0b: W^T bf16 prep. Wt[o_global][k] = bf16(W[k][o]).
// ---------------------------------------------------------------------------
__global__ __launch_bounds__(256) void wprep_kernel(
    const float* __restrict__ WQ, const float* __restrict__ WK,
    const float* __restrict__ WV, u16* __restrict__ Wt) {
  const int o = blockIdx.x;          // 0..767
  const int which = o >> 8, oo = o & 255;
  const float* W = (which == 0) ? WQ : ((which == 1) ? WK : WV);
  const int k = threadIdx.x;
  Wt[(size_t)o * 256 + k] = f2bf(W[(size_t)k * 256 + oo]);
}

// ---------------------------------------------------------------------------
// Kernel 1: QKV projection.  grid (64 rowblocks, 12 col-chunks).
//  Q written in 32x32x16-MFMA B-fragment layout (R2/R3-validated):
//   Qb[((row>>5)*16 + (col>>4))*512 + ((col>>3)&1)*256 + (row&31)*8 + (col&7)]
// ---------------------------------------------------------------------------
__global__ __launch_bounds__(256) void qkv_kernel(
    const u16* __restrict__ Xb, const u16* __restrict__ Wt,
    const float* __restrict__ bQ, const float* __restrict__ bK,
    const float* __restrict__ bV,
    u16* __restrict__ Qb, u16* __restrict__ Kb, u16* __restrict__ Vt) {
  __shared__ u16 wt[64 * 256];
  const int tid = threadIdx.x;
  const int lane = tid & 63;
  const int wave = tid >> 6;
  const int l15 = lane & 15;
  const int q4 = lane >> 4;
  const int rb = blockIdx.x;
  const int ch = blockIdx.y;
  const int which = ch >> 2;
  const int c0 = (ch & 3) * 64;
  const float* bias = (which == 0) ? bQ : ((which == 1) ? bK : bV);

  bf16x8 xa[2][8];
#pragma unroll
  for (int mt = 0; mt < 2; ++mt) {
    const int row = rb * 128 + wave * 32 + mt * 16 + l15;
#pragma unroll
    for (int kc = 0; kc < 8; ++kc)
      xa[mt][kc] = *(const bf16x8*)(Xb + (size_t)row * 256 + kc * 32 + q4 * 8);
  }
  {
    const u16* Wsrc = Wt + (size_t)(which * 256 + c0) * 256;
    const int rb0 = wave * 16;
#pragma unroll
    for (int i = 0; i < 8; ++i) {
      int r = rb0 + i * 2 + (lane >> 5);
      int c = (lane & 31) ^ (r & 7);
      async16(Wsrc + (size_t)r * 256 + c * 8, wt + (rb0 + i * 2) * 256);
    }
  }
  asm volatile("s_waitcnt vmcnt(0)" ::: "memory");
  __syncthreads();

  f32x4 acc[2][4];
#pragma unroll
  for (int mt = 0; mt < 2; ++mt)
#pragma unroll
    for (int nt = 0; nt < 4; ++nt) acc[mt][nt] = (f32x4){0.f, 0.f, 0.f, 0.f};

#pragma unroll
  for (int kc = 0; kc < 8; ++kc) {
#pragma unroll
    for (int nt = 0; nt < 4; ++nt) {
      bf16x8 wf = *(const bf16x8*)(wt + (nt * 16 + l15) * 256 +
                                   (((kc * 4 + q4) ^ (l15 & 7)) * 8));
#pragma unroll
      for (int mt = 0; mt < 2; ++mt)
        acc[mt][nt] = mfma16(xa[mt][kc], wf, acc[mt][nt]);
    }
  }
  float bc[4];
#pragma unroll
  for (int nt = 0; nt < 4; ++nt) bc[nt] = bias[c0 + nt * 16 + l15];

#pragma unroll
  for (int mt = 0; mt < 2; ++mt)
#pragma unroll
    for (int nt = 0; nt < 4; ++nt)
#pragma unroll
      for (int r = 0; r < 4; ++r) {
        float v = acc[mt][nt][r] + bc[nt];
        int grow = rb * 128 + wave * 32 + mt * 16 + q4 * 4 + r;
        int gc = c0 + nt * 16 + l15;
        if (which == 2)      Vt[(size_t)gc * NTOK + grow] = f2bf(v);
        else if (which == 1) Kb[(size_t)grow * 256 + gc] = f2bf(v);
        else                 Qb[(size_t)((grow >> 5) * 16 + (gc >> 4)) * 512 +
                                ((gc >> 3) & 1) * 256 + (grow & 31) * 8 +
                                (gc & 7)] = f2bf(v);
      }
}

// ---------------------------------------------------------------------------
// Kernel 2: flash attention, M=32/wave, 32x32x16 MFMA, 8-wave blocks.
//  R4 post-mortem: M=16 is LDS-read-pipe bound (~116us of the 138); only M
//  cuts reads/FLOP; R3's M=32 had the right economics (floor ~56us) but a
//  drain-everything schedule (40% efficiency). This version keeps M=32 and
//  fixes the schedule:
//   * grid (8 sp, 32 rb) = 256 blocks = exactly 1/CU; linear%8==sp -> each
//     split's 1MB K/V slice is L2-resident on one XCD.
//   * ring-3 LDS (K 48K, V 48K, kp 3K = 99KB; free at 1 block/CU), prefetch
//     distance 2.
//   * ONE barrier + ONE counted vmcnt per iter, no drains: each wave issues
//     exactly 4 DMAs/tile (K,K,V,V; wave0 +kp last) so vmcnt(4)/(5) at iter
//     top guarantees tile t landed while tile t+1 stays in flight. Slot
//     rotation hazard (writes of tile t+2 vs reads of tile t-1) is fenced by
//     the same barrier. Last iter drains vmcnt(0) so no DMA outlives block.
//  All swizzles / pack / decay-MFMA / epilogue carried verbatim from the
//  refcheck-passing R2/R3 kernels.
// ---------------------------------------------------------------------------
__global__ __launch_bounds__(512, 2) void attn_kernel(
    const u16* __restrict__ Qb, const u16* __restrict__ Kb,
    const u16* __restrict__ Vt, const u16* __restrict__ Qp,
    const u16* __restrict__ Kp, u16* __restrict__ Op,
    float* __restrict__ ml) {
  __shared__ u16 kbuf[3][BN * 256];               // 16 KB x3  [key][256]
  __shared__ u16 vbuf[3][256 * BN];               // 16 KB x3  [feat][32]
  __shared__ u16 kpbuf[3][BN * 16];               // 1 KB x3   [key][16]

  const int tid = threadIdx.x;
  const int lane = tid & 63;
  const int wave = tid >> 6;
  const int l31 = lane & 31;
  const int h5 = lane >> 5;
  const int sp = blockIdx.x;
  const int rb = blockIdx.y;
  const int q0 = rb * 256;
  const int wrow = wave * 32;

  // per-wave duty: K rows [4w,4w+4) (2 DMAs), V feats [32w,32w+32) (2 DMAs),
  // wave0 additionally kp (1 DMA, issued LAST).
#define STAGE(T, S_)                                                          \
  do {                                                                        \
    const int key0_ = sp * SPLEN + (T) * BN;                                  \
    _Pragma("unroll")                                                         \
    for (int j = 0; j < 2; ++j) {                                             \
      int r = wave * 4 + j * 2 + (lane >> 5);                                 \
      int c = (lane & 31) ^ (r & 7);                                          \
      async16(Kb + (size_t)(key0_ + r) * 256 + c * 8,                         \
              &kbuf[S_][(wave * 4 + j * 2) * 256]);                           \
    }                                                                         \
    _Pragma("unroll")                                                         \
    for (int j = 0; j < 2; ++j) {                                             \
      int f = wave * 32 + j * 16 + (lane >> 2);                               \
      int c = (lane & 3) ^ ((f >> 1) & 3);                                    \
      async16(Vt + (size_t)f * NTOK + key0_ + c * 8,                          \
              &vbuf[S_][(wave * 32 + j * 16) * 32]);                          \
    }                                                                         \
    if (wave == 0)                                                            \
      async16(Kp + (size_t)(key0_ + (lane >> 1)) * 16 + (lane & 1) * 8,       \
              &kpbuf[S_][0]);                                                 \
  } while (0)

  // ---- Q fragments (loop-invariant, coalesced from frag-layout Qb) ----
  const int rb32 = rb * 8 + wave;
  bf16x8 qa[16];
#pragma unroll
  for (int kc = 0; kc < 16; ++kc)
    qa[kc] = *(const bf16x8*)(Qb + ((size_t)(rb32 * 16 + kc) * 64 + lane) * 8);

  // position B-fragment for this lane's qrow (col = lane&31 in S^T layout)
  const bf16x8 qp = *(const bf16x8*)(Qp + (size_t)(q0 + wrow + l31) * 16 +
                                     h5 * 8);

  f32x16 O[8];
#pragma unroll
  for (int ft = 0; ft < 8; ++ft)
#pragma unroll
    for (int r = 0; r < 16; ++r) O[ft][r] = 0.f;
  float lrow = 0.f;

  const int kswz = l31 & 7;
  const int vswz = (l31 >> 1) & 3;

  STAGE(0, 0);
  STAGE(1, 1);

  int cur = 0;
#pragma unroll 1
  for (int t = 0; t < ITERS; ++t) {
    // ---- wait tile t only (tile t+1 stays in flight), single barrier ----
    if (t + 1 < ITERS) {
      if (wave == 0) asm volatile("s_waitcnt vmcnt(5)" ::: "memory");
      else           asm volatile("s_waitcnt vmcnt(4)" ::: "memory");
    } else {
      asm volatile("s_waitcnt vmcnt(0)" ::: "memory");
    }
    __builtin_amdgcn_s_barrier();

    // ---- issue tile t+2 into slot (cur+2)%3 ----
    if (t + 2 < ITERS) {
      const int s2 = (cur >= 1) ? (cur - 1) : 2;
      STAGE(t + 2, s2);
    }

    // ---- T = decay-exponent MFMA ----
    f32x16 T;
#pragma unroll
    for (int r = 0; r < 16; ++r) T[r] = 0.f;
    {
      bf16x8 kpf = *(const bf16x8*)(&kpbuf[cur][l31 * 16 + h5 * 8]);
      T = mfma32(kpf, qp, T);
    }

    // ---- S^T = K Q^T : D[key][qrow], 32 keys x 32 rows ----
    f32x16 S;
#pragma unroll
    for (int r = 0; r < 16; ++r) S[r] = 0.f;
    __builtin_amdgcn_s_setprio(1);
#pragma unroll
    for (int kc = 0; kc < 16; ++kc) {
      bf16x8 kf = *(const bf16x8*)(&kbuf[cur][l31 * 256 +
                                   (((2 * kc + h5) ^ kswz) * 8)]);
      S = mfma32(kf, qa[kc], S);
    }
    __builtin_amdgcn_s_setprio(0);

    // ---- softmax: dec = exp2(-t*log2e + DECC); p = exp2(S*dec) ----
#pragma unroll
    for (int r = 0; r < 16; ++r) {
      float dec = exp2_hw(fmaf(T[r], -LOG2E, DECC));
      float p = exp2_hw(S[r] * dec);
      S[r] = p;
      lrow += p;
    }

    // ---- pack P to bf16 A-frags in-register (cvt_pk + permlane32_swap) ----
    uint32_t w0, w1, w2, w3, w4, w5, w6, w7;
    asm("v_cvt_pk_bf16_f32 %0, %1, %2" : "=v"(w0) : "v"(S[0]),  "v"(S[1]));
    asm("v_cvt_pk_bf16_f32 %0, %1, %2" : "=v"(w1) : "v"(S[2]),  "v"(S[3]));
    asm("v_cvt_pk_bf16_f32 %0, %1, %2" : "=v"(w2) : "v"(S[4]),  "v"(S[5]));
    asm("v_cvt_pk_bf16_f32 %0, %1, %2" : "=v"(w3) : "v"(S[6]),  "v"(S[7]));
    asm("v_cvt_pk_bf16_f32 %0, %1, %2" : "=v"(w4) : "v"(S[8]),  "v"(S[9]));
    asm("v_cvt_pk_bf16_f32 %0, %1, %2" : "=v"(w5) : "v"(S[10]), "v"(S[11]));
    asm("v_cvt_pk_bf16_f32 %0, %1, %2" : "=v"(w6) : "v"(S[12]), "v"(S[13]));
    asm("v_cvt_pk_bf16_f32 %0, %1, %2" : "=v"(w7) : "v"(S[14]), "v"(S[15]));
    asm volatile("v_permlane32_swap_b32 %0, %1" : "+v"(w2), "+v"(w0));
    asm volatile("v_permlane32_swap_b32 %0, %1" : "+v"(w3), "+v"(w1));
    asm volatile("v_permlane32_swap_b32 %0, %1" : "+v"(w6), "+v"(w4));
    asm volatile("v_permlane32_swap_b32 %0, %1" : "+v"(w7), "+v"(w5));
    PW pa0, pa1;
    pa0.u[0] = w0; pa0.u[1] = w1; pa0.u[2] = w2; pa0.u[3] = w3;  // keys 0..15
    pa1.u[0] = w4; pa1.u[1] = w5; pa1.u[2] = w6; pa1.u[3] = w7;  // keys 16..31

    // ---- O += P V (full 256 features, 8 ft-blocks of 32) ----
    __builtin_amdgcn_s_setprio(1);
#pragma unroll
    for (int kh = 0; kh < 2; ++kh) {
      const bf16x8 pa = kh ? pa1.v : pa0.v;
#pragma unroll
      for (int ft = 0; ft < 8; ++ft) {
        bf16x8 vf = *(const bf16x8*)(&vbuf[cur][(ft * 32 + l31) * 32 +
                                     (((2 * kh + h5) ^ vswz) * 8)]);
        O[ft] = mfma32(pa, vf, O[ft]);
      }
    }
    __builtin_amdgcn_s_setprio(0);

    cur = (cur == 2) ? 0 : (cur + 1);
  }

  // ---- epilogue ----
  float lsum = lrow + __shfl_xor(lrow, 32);
#pragma unroll
  for (int ft = 0; ft < 8; ++ft)
#pragma unroll
    for (int r = 0; r < 16; ++r) {
      int row = q0 + wrow + (r & 3) + 8 * (r >> 2) + 4 * h5;
      Op[((size_t)sp * NTOK + row) * 256 + ft * 32 + l31] = f2bf(O[ft][r]);
    }
  if (lane < 32)
    ml[sp * NTOK + q0 + wrow + lane] = lsum;
#undef STAGE
}

// ---------------------------------------------------------------------------
// Kernel 3: combine splits: H = (sum O_s) / (1 + sum l_s) + residual.
// ---------------------------------------------------------------------------
__global__ __launch_bounds__(256) void combine_kernel(
    const float* __restrict__ X, const u16* __restrict__ Op,
    const float* __restrict__ ml, float* __restrict__ out) {
  const int row = blockIdx.x;
  const int f = threadIdx.x;
  float den = 1.f, num = 0.f;
#pragma unroll
  for (int s = 0; s < KSPLIT; ++s) {
    den += ml[s * NTOK + row];
    num += bf2f(Op[((size_t)s * NTOK + row) * 256 + f]);
  }
  out[(size_t)row * 256 + f] = num / den + X[(size_t)row * XSTRIDE + f];
}

// ---------------------------------------------------------------------------
extern "C" void kernel_launch(void* const* d_in, const int* in_sizes, int n_in,
                              void* d_out, int out_size, void* d_ws, size_t ws_size,
                              hipStream_t stream) {
  (void)in_sizes; (void)n_in; (void)out_size; (void)ws_size;
  const float* X  = (const float*)d_in[0];
  const float* WQ = (const float*)d_in[1];
  const float* bQ = (const float*)d_in[2];
  const float* WK = (const float*)d_in[3];
  const float* bK = (const float*)d_in[4];
  const float* WV = (const float*)d_in[5];
  const float* bV = (const float*)d_in[6];
  float* out = (float*)d_out;
  char* ws = (char*)d_ws;

  // ws: Qb 4M | Kb 4M | Vt 4M | Qp 256K | Kp 256K | Wt 384K | Xb 4M |
  //     ml 512K | Op 32M
  u16*   Qb = (u16*)(ws);
  u16*   Kb = (u16*)(ws + ((size_t)4 << 20));
  u16*   Vt = (u16*)(ws + ((size_t)8 << 20));
  u16*   Qp = (u16*)(ws + ((size_t)12 << 20));
  u16*   Kp = (u16*)(ws + ((size_t)12 << 20) + 262144);
  u16*   Wt = (u16*)(ws + ((size_t)12 << 20) + 524288);
  u16*   Xb = (u16*)(ws + ((size_t)12 << 20) + 524288 + 393216);
  float* ml = (float*)(ws + ((size_t)16 << 20) + 524288 + 393216);
  u16*   Op = (u16*)(ws + ((size_t)16 << 20) + 524288 + 393216 + 524288);

  pos_kernel<<<dim3(NTOK / 256), dim3(256), 0, stream>>>(X, Qp, Kp);
  xb_kernel<<<dim3(NTOK / 8), dim3(256), 0, stream>>>(X, Xb);
  wprep_kernel<<<dim3(768), dim3(256), 0, stream>>>(WQ, WK, WV, Wt);
  qkv_kernel<<<dim3(64, 12), dim3(256), 0, stream>>>(Xb, Wt, bQ, bK, bV,
                                                     Qb, Kb, Vt);
  attn_kernel<<<dim3(KSPLIT, NTOK / 256), dim3(512), 0, stream>>>(
      Qb, Kb, Vt, Qp, Kp, Op, ml);
  combine_kernel<<<dim3(NTOK), dim3(256), 0, stream>>>(X, Op, ml, out);
}

// Round 6
// 205.731 us; speedup vs baseline: 1.3978x; 1.0145x over previous
//
#include <hip/hip_runtime.h>
#include <hip/hip_bf16.h>
#include <stdint.h>

#define NTOK 8192
#define XSTRIDE 259
#define LOG2E 1.4426950408889634f
#define DECC (-3.4712336270551023f)   /* -4 + log2(log2 e) */
#define KSPLIT 8
#define SPLEN (NTOK / KSPLIT)   /* 1024 */
#define BN 64
#define ITERS (SPLEN / BN)      /* 16 */

typedef __bf16 bf16x8 __attribute__((ext_vector_type(8)));
typedef float f32x4 __attribute__((ext_vector_type(4)));
typedef float f32x16 __attribute__((ext_vector_type(16)));
typedef unsigned short u16;

union BF8 { u16 u[8]; bf16x8 v; };
union PW  { uint32_t u[4]; bf16x8 v; };

__device__ __forceinline__ u16 f2bf(float f) {
  uint32_t u = __float_as_uint(f);
  u += 0x7FFFu + ((u >> 16) & 1u);
  return (u16)(u >> 16);
}
__device__ __forceinline__ float bf2f(u16 h) {
  return __uint_as_float(((uint32_t)h) << 16);
}
__device__ __forceinline__ float exp2_hw(float x) {
  float r; asm("v_exp_f32 %0, %1" : "=v"(r) : "v"(x)); return r;
}
__device__ __forceinline__ f32x4 mfma16(bf16x8 a, bf16x8 b, f32x4 c) {
  return __builtin_amdgcn_mfma_f32_16x16x32_bf16(a, b, c, 0, 0, 0);
}
__device__ __forceinline__ f32x16 mfma32(bf16x8 a, bf16x8 b, f32x16 c) {
  return __builtin_amdgcn_mfma_f32_32x32x16_bf16(a, b, c, 0, 0, 0);
}
__device__ __forceinline__ void async16(const void* g, void* l) {
  __builtin_amdgcn_global_load_lds(
      (const __attribute__((address_space(1))) uint32_t*)g,
      (__attribute__((address_space(3))) uint32_t*)l, 16, 0, 0);
}
__device__ __forceinline__ void bsplit(float v, u16& h, u16& l) {
  h = f2bf(v);
  l = f2bf(v - bf2f(h));
}

// ---------------------------------------------------------------------------
// Kernel 0: X -> bf16 once, FUSED with position-feature prep (pos merged in:
//  threads 0..7 of each block handle the block's 8 rows' Qp/Kp vectors).
// ---------------------------------------------------------------------------
__global__ __launch_bounds__(256) void xb_kernel(
    const float* __restrict__ X, u16* __restrict__ Xb,
    u16* __restrict__ Qp, u16* __restrict__ Kp) {
  const int t = threadIdx.x;
  const int row = blockIdx.x * 8 + (t >> 5);
  const int c0 = (t & 31) * 8;
  const float* xp = X + (size_t)row * XSTRIDE + c0;
  union { u16 u[8]; uint4 v; } o;
#pragma unroll
  for (int j = 0; j < 8; ++j) o.u[j] = f2bf(xp[j]);
  *(uint4*)(Xb + (size_t)row * 256 + c0) = o.v;

  if (t < 8) {
    const int r = blockIdx.x * 8 + t;
    const float* pp = X + (size_t)r * XSTRIDE + 256;
    const float x = pp[0], y = pp[1], z = pp[2];
    const float w = 0.5f * (x * x + y * y + z * z);
    u16 xh, xl, yh, yl, zh, zl, wh, wl;
    bsplit(x, xh, xl); bsplit(y, yh, yl); bsplit(z, zh, zl); bsplit(w, wh, wl);
    const u16 one = 0x3F80u;
    const u16 SGN = 0x8000u;
    union { u16 u[16]; uint4 v4[2]; } uq, uk;
    uq.u[0] = wh;  uk.u[0] = one;
    uq.u[1] = wl;  uk.u[1] = one;
    uq.u[2] = one; uk.u[2] = wh;
    uq.u[3] = one; uk.u[3] = wl;
    uq.u[4] = (u16)(xh ^ SGN); uk.u[4] = xh;
    uq.u[5] = (u16)(xh ^ SGN); uk.u[5] = xl;
    uq.u[6] = (u16)(xl ^ SGN); uk.u[6] = xh;
    uq.u[7] = (u16)(yh ^ SGN); uk.u[7] = yh;
    uq.u[8] = (u16)(yh ^ SGN); uk.u[8] = yl;
    uq.u[9] = (u16)(yl ^ SGN); uk.u[9] = yh;
    uq.u[10] = (u16)(zh ^ SGN); uk.u[10] = zh;
    uq.u[11] = (u16)(zh ^ SGN); uk.u[11] = zl;
    uq.u[12] = (u16)(zl ^ SGN); uk.u[12] = zh;
    uq.u[13] = 0; uk.u[13] = 0;
    uq.u[14] = 0; uk.u[14] = 0;
    uq.u[15] = 0; uk.u[15] = 0;
    ((uint4*)Qp)[r * 2] = uq.v4[0];
    ((uint4*)Qp)[r * 2 + 1] = uq.v4[1];
    ((uint4*)Kp)[r * 2] = uk.v4[0];
    ((uint4*)Kp)[r * 2 + 1] = uk.v4[1];
  }
}

// ---------------------------------------------------------------------------
// Kernel 0b: W^T bf16 prep. Wt[o_global][k] = bf16(W[k][o]).
// ---------------------------------------------------------------------------
__global__ __launch_bounds__(256) void wprep_kernel(
    const float* __restrict__ WQ, const float* __restrict__ WK,
    const float* __restrict__ WV, u16* __restrict__ Wt) {
  const int o = blockIdx.x;          // 0..767
  const int which = o >> 8, oo = o & 255;
  const float* W = (which == 0) ? WQ : ((which == 1) ? WK : WV);
  const int k = threadIdx.x;
  Wt[(size_t)o * 256 + k] = f2bf(W[(size_t)k * 256 + oo]);
}

// ---------------------------------------------------------------------------
// Kernel 1: QKV projection, grid (64 rowblocks, 12 col-chunks).
//  R5 audit: the old epilogue issued 12M scalar u16 stores; the Vt pattern
//  scattered 64 lanes across 16KB-strided addresses (~16 L2 transactions per
//  store instr). NEW: bounce the C-tile through LDS (reuse dead wt buffer)
//  and store coalesced dwordx4 (~16x fewer write transactions, same bytes).
//  Q written in 32x32x16-MFMA B-fragment layout (R2/R5-validated).
// ---------------------------------------------------------------------------
__global__ __launch_bounds__(256) void qkv_kernel(
    const u16* __restrict__ Xb, const u16* __restrict__ Wt,
    const float* __restrict__ bQ, const float* __restrict__ bK,
    const float* __restrict__ bV,
    u16* __restrict__ Qb, u16* __restrict__ Kb, u16* __restrict__ Vt) {
  __shared__ u16 smem[64 * 256];   // 32KB: W staging, then reused as C-tile
  const int tid = threadIdx.x;
  const int lane = tid & 63;
  const int wave = tid >> 6;
  const int l15 = lane & 15;
  const int q4 = lane >> 4;
  const int rb = blockIdx.x;
  const int ch = blockIdx.y;
  const int which = ch >> 2;
  const int c0 = (ch & 3) * 64;
  const float* bias = (which == 0) ? bQ : ((which == 1) ? bK : bV);

  bf16x8 xa[2][8];
#pragma unroll
  for (int mt = 0; mt < 2; ++mt) {
    const int row = rb * 128 + wave * 32 + mt * 16 + l15;
#pragma unroll
    for (int kc = 0; kc < 8; ++kc)
      xa[mt][kc] = *(const bf16x8*)(Xb + (size_t)row * 256 + kc * 32 + q4 * 8);
  }
  {
    const u16* Wsrc = Wt + (size_t)(which * 256 + c0) * 256;
    const int rb0 = wave * 16;
#pragma unroll
    for (int i = 0; i < 8; ++i) {
      int r = rb0 + i * 2 + (lane >> 5);
      int c = (lane & 31) ^ (r & 7);
      async16(Wsrc + (size_t)r * 256 + c * 8, smem + (rb0 + i * 2) * 256);
    }
  }
  asm volatile("s_waitcnt vmcnt(0)" ::: "memory");
  __syncthreads();

  f32x4 acc[2][4];
#pragma unroll
  for (int mt = 0; mt < 2; ++mt)
#pragma unroll
    for (int nt = 0; nt < 4; ++nt) acc[mt][nt] = (f32x4){0.f, 0.f, 0.f, 0.f};

#pragma unroll
  for (int kc = 0; kc < 8; ++kc) {
#pragma unroll
    for (int nt = 0; nt < 4; ++nt) {
      bf16x8 wf = *(const bf16x8*)(smem + (nt * 16 + l15) * 256 +
                                   (((kc * 4 + q4) ^ (l15 & 7)) * 8));
#pragma unroll
      for (int mt = 0; mt < 2; ++mt)
        acc[mt][nt] = mfma16(xa[mt][kc], wf, acc[mt][nt]);
    }
  }
  float bc[4];
#pragma unroll
  for (int nt = 0; nt < 4; ++nt) bc[nt] = bias[c0 + nt * 16 + l15];

  __syncthreads();   // all waves done reading W tile; smem reused below
  const int grow0 = rb * 128;

  if (which == 2) {
    // transposed tile Tv[col(64)][row(128) + pad8] -> coalesced feat-major
#pragma unroll
    for (int mt = 0; mt < 2; ++mt)
#pragma unroll
      for (int nt = 0; nt < 4; ++nt) {
        const int lcol = nt * 16 + l15;
        const int lrow0 = wave * 32 + mt * 16 + q4 * 4;
        union { u16 u[4]; uint2 w; } p;
#pragma unroll
        for (int r = 0; r < 4; ++r) p.u[r] = f2bf(acc[mt][nt][r] + bc[nt]);
        *(uint2*)(smem + lcol * 136 + lrow0) = p.w;
      }
    __syncthreads();
#pragma unroll
    for (int i = 0; i < 4; ++i) {
      int chn = i * 256 + tid;            // 1024 chunks of 16B
      int lcol = chn >> 4, s = chn & 15;
      uint4 d = *(const uint4*)(smem + lcol * 136 + s * 8);
      *(uint4*)(Vt + (size_t)(c0 + lcol) * NTOK + grow0 + s * 8) = d;
    }
  } else {
    // row-major tile T[row(128)][col(64) + pad8]
#pragma unroll
    for (int mt = 0; mt < 2; ++mt)
#pragma unroll
      for (int nt = 0; nt < 4; ++nt)
#pragma unroll
        for (int r = 0; r < 4; ++r)
          smem[(wave * 32 + mt * 16 + q4 * 4 + r) * 72 + nt * 16 + l15] =
              f2bf(acc[mt][nt][r] + bc[nt]);
    __syncthreads();
#pragma unroll
    for (int i = 0; i < 4; ++i) {
      int chn = i * 256 + tid;            // 1024 chunks of 16B
      int lrow = chn >> 3, g = chn & 7;
      uint4 d = *(const uint4*)(smem + lrow * 72 + g * 8);
      int grow = grow0 + lrow, gc = c0 + g * 8;
      if (which == 1)
        *(uint4*)(Kb + (size_t)grow * 256 + gc) = d;
      else
        *(uint4*)(Qb + (size_t)((grow >> 5) * 16 + (gc >> 4)) * 512 +
                  ((gc >> 3) & 1) * 256 + (grow & 31) * 8) = d;
    }
  }
}

// ---------------------------------------------------------------------------
// Kernel 2: flash attention, M=32/wave, 32x32x16 MFMA, 8-wave blocks.
//  R5 falsifier fired (119 vs predicted 75-95): scheduling polish exhausted;
//  remaining per-iter cost is fixed events (barrier skew, vmcnt, stage burst,
//  loop) that 2 waves/SIMD can't hide and the 256-reg cap forbids more TLP.
//  This round AMORTIZES them: BN=64 key-tiles (2 x 32-key sub-phases per
//  barrier), double-buffered (132KB LDS, 1 block/CU), vmcnt(0)+barrier once
//  per 64 keys. Identical LDS-read economics per key; half the fixed events.
//  grid (8 sp, 32 rb): linear%8==sp -> split pinned to one XCD (L2-resident).
//  V LDS swizzle generalized to granule^(feat&7) on both sides (BN=64 rows
//  are 128B). All validated pieces (K swizzle, decay-MFMA, cvt_pk+permlane
//  pack, epilogue mapping) carried verbatim from refcheck-passing R5.
// ---------------------------------------------------------------------------
__global__ __launch_bounds__(512, 2) void attn_kernel(
    const u16* __restrict__ Qb, const u16* __restrict__ Kb,
    const u16* __restrict__ Vt, const u16* __restrict__ Qp,
    const u16* __restrict__ Kp, u16* __restrict__ Op,
    float* __restrict__ ml) {
  __shared__ u16 kbuf[2][BN * 256];               // 32 KB x2  [key][256]
  __shared__ u16 vbuf[2][256 * BN];               // 32 KB x2  [feat][64]
  __shared__ u16 kpbuf[2][BN * 16];               // 2 KB x2   [key][16]

  const int tid = threadIdx.x;
  const int lane = tid & 63;
  const int wave = tid >> 6;
  const int l31 = lane & 31;
  const int h5 = lane >> 5;
  const int sp = blockIdx.x;
  const int rb = blockIdx.y;
  const int q0 = rb * 256;
  const int wrow = wave * 32;

  // per-wave duty per 64-key tile: 4 K DMAs (2 rows each), 4 V DMAs (8 feat
  // rows each), wave0 +2 kp DMAs. vmcnt(0) at iter top (only tile t in
  // flight, issued one full iteration earlier).
#define STAGE(T, S_)                                                          \
  do {                                                                        \
    const int key0_ = sp * SPLEN + (T) * BN;                                  \
    _Pragma("unroll")                                                         \
    for (int j = 0; j < 4; ++j) {                                             \
      int r = wave * 8 + j * 2 + (lane >> 5);                                 \
      int c = (lane & 31) ^ (r & 7);                                          \
      async16(Kb + (size_t)(key0_ + r) * 256 + c * 8,                         \
              &kbuf[S_][(wave * 8 + j * 2) * 256]);                           \
    }                                                                         \
    _Pragma("unroll")                                                         \
    for (int j = 0; j < 4; ++j) {                                             \
      int f = wave * 32 + j * 8 + (lane >> 3);                                \
      int c = (lane & 7) ^ (f & 7);                                           \
      async16(Vt + (size_t)f * NTOK + key0_ + c * 8,                          \
              &vbuf[S_][(wave * 32 + j * 8) * BN]);                           \
    }                                                                         \
    if (wave == 0) {                                                          \
      _Pragma("unroll")                                                       \
      for (int hh = 0; hh < 2; ++hh)                                          \
        async16(Kp + (size_t)(key0_ + hh * 32 + (lane >> 1)) * 16 +           \
                    (lane & 1) * 8,                                           \
                &kpbuf[S_][hh * 32 * 16]);                                    \
    }                                                                         \
  } while (0)

  // ---- Q fragments (loop-invariant, coalesced from frag-layout Qb) ----
  const int rb32 = rb * 8 + wave;
  bf16x8 qa[16];
#pragma unroll
  for (int kc = 0; kc < 16; ++kc)
    qa[kc] = *(const bf16x8*)(Qb + ((size_t)(rb32 * 16 + kc) * 64 + lane) * 8);

  // position B-fragment for this lane's qrow (col = lane&31 in S^T layout)
  const bf16x8 qp = *(const bf16x8*)(Qp + (size_t)(q0 + wrow + l31) * 16 +
                                     h5 * 8);

  f32x16 O[8];
#pragma unroll
  for (int ft = 0; ft < 8; ++ft)
#pragma unroll
    for (int r = 0; r < 16; ++r) O[ft][r] = 0.f;
  float lrow = 0.f;

  const int swz = l31 & 7;

  STAGE(0, 0);

#pragma unroll 1
  for (int t = 0; t < ITERS; ++t) {
    const int slot = t & 1;
    asm volatile("s_waitcnt vmcnt(0)" ::: "memory");
    __builtin_amdgcn_s_barrier();
    if (t + 1 < ITERS) STAGE(t + 1, slot ^ 1);

#pragma unroll
    for (int sub = 0; sub < 2; ++sub) {
      // ---- T = decay-exponent MFMA ----
      f32x16 T;
#pragma unroll
      for (int r = 0; r < 16; ++r) T[r] = 0.f;
      {
        bf16x8 kpf = *(const bf16x8*)(&kpbuf[slot][(sub * 32 + l31) * 16 +
                                      h5 * 8]);
        T = mfma32(kpf, qp, T);
      }

      // ---- S^T = K Q^T : D[key][qrow], 32 keys x 32 rows ----
      f32x16 S;
#pragma unroll
      for (int r = 0; r < 16; ++r) S[r] = 0.f;
      __builtin_amdgcn_s_setprio(1);
#pragma unroll
      for (int kc = 0; kc < 16; ++kc) {
        bf16x8 kf = *(const bf16x8*)(&kbuf[slot][(sub * 32 + l31) * 256 +
                                     (((2 * kc + h5) ^ swz) * 8)]);
        S = mfma32(kf, qa[kc], S);
      }
      __builtin_amdgcn_s_setprio(0);

      // ---- softmax: dec = exp2(-t*log2e + DECC); p = exp2(S*dec) ----
#pragma unroll
      for (int r = 0; r < 16; ++r) {
        float dec = exp2_hw(fmaf(T[r], -LOG2E, DECC));
        float p = exp2_hw(S[r] * dec);
        S[r] = p;
        lrow += p;
      }

      // ---- pack P to bf16 A-frags in-register ----
      uint32_t w0, w1, w2, w3, w4, w5, w6, w7;
      asm("v_cvt_pk_bf16_f32 %0, %1, %2" : "=v"(w0) : "v"(S[0]),  "v"(S[1]));
      asm("v_cvt_pk_bf16_f32 %0, %1, %2" : "=v"(w1) : "v"(S[2]),  "v"(S[3]));
      asm("v_cvt_pk_bf16_f32 %0, %1, %2" : "=v"(w2) : "v"(S[4]),  "v"(S[5]));
      asm("v_cvt_pk_bf16_f32 %0, %1, %2" : "=v"(w3) : "v"(S[6]),  "v"(S[7]));
      asm("v_cvt_pk_bf16_f32 %0, %1, %2" : "=v"(w4) : "v"(S[8]),  "v"(S[9]));
      asm("v_cvt_pk_bf16_f32 %0, %1, %2" : "=v"(w5) : "v"(S[10]), "v"(S[11]));
      asm("v_cvt_pk_bf16_f32 %0, %1, %2" : "=v"(w6) : "v"(S[12]), "v"(S[13]));
      asm("v_cvt_pk_bf16_f32 %0, %1, %2" : "=v"(w7) : "v"(S[14]), "v"(S[15]));
      asm volatile("v_permlane32_swap_b32 %0, %1" : "+v"(w2), "+v"(w0));
      asm volatile("v_permlane32_swap_b32 %0, %1" : "+v"(w3), "+v"(w1));
      asm volatile("v_permlane32_swap_b32 %0, %1" : "+v"(w6), "+v"(w4));
      asm volatile("v_permlane32_swap_b32 %0, %1" : "+v"(w7), "+v"(w5));
      PW pa0, pa1;
      pa0.u[0] = w0; pa0.u[1] = w1; pa0.u[2] = w2; pa0.u[3] = w3;
      pa1.u[0] = w4; pa1.u[1] = w5; pa1.u[2] = w6; pa1.u[3] = w7;

      // ---- O += P V (full 256 features, 8 ft-blocks of 32) ----
      __builtin_amdgcn_s_setprio(1);
#pragma unroll
      for (int kh = 0; kh < 2; ++kh) {
        const bf16x8 pa = kh ? pa1.v : pa0.v;
        const int khh = sub * 2 + kh;
#pragma unroll
        for (int ft = 0; ft < 8; ++ft) {
          bf16x8 vf = *(const bf16x8*)(&vbuf[slot][(ft * 32 + l31) * BN +
                                       (((2 * khh + h5) ^ swz) * 8)]);
          O[ft] = mfma32(pa, vf, O[ft]);
        }
      }
      __builtin_amdgcn_s_setprio(0);
    }
  }

  // ---- epilogue ----
  float lsum = lrow + __shfl_xor(lrow, 32);
#pragma unroll
  for (int ft = 0; ft < 8; ++ft)
#pragma unroll
    for (int r = 0; r < 16; ++r) {
      int row = q0 + wrow + (r & 3) + 8 * (r >> 2) + 4 * h5;
      Op[((size_t)sp * NTOK + row) * 256 + ft * 32 + l31] = f2bf(O[ft][r]);
    }
  if (lane < 32)
    ml[sp * NTOK + q0 + wrow + lane] = lsum;
#undef STAGE
}

// ---------------------------------------------------------------------------
// Kernel 3: combine splits, vectorized: thread handles 2 features (uint =
//  2 bf16 loads, float2 store). Block = 2 rows, grid 4096.
// ---------------------------------------------------------------------------
__global__ __launch_bounds__(256) void combine_kernel(
    const float* __restrict__ X, const u16* __restrict__ Op,
    const float* __restrict__ ml, float* __restrict__ out) {
  const int row = blockIdx.x * 2 + (threadIdx.x >> 7);
  const int f2 = threadIdx.x & 127;
  float den = 1.f, n0 = 0.f, n1 = 0.f;
#pragma unroll
  for (int s = 0; s < KSPLIT; ++s) {
    den += ml[s * NTOK + row];
    uint32_t v = *(const uint32_t*)(Op + ((size_t)s * NTOK + row) * 256 +
                                    f2 * 2);
    n0 += bf2f((u16)v);
    n1 += bf2f((u16)(v >> 16));
  }
  const float inv = 1.f / den;
  float2 o;
  o.x = n0 * inv + X[(size_t)row * XSTRIDE + f2 * 2];
  o.y = n1 * inv + X[(size_t)row * XSTRIDE + f2 * 2 + 1];
  *(float2*)(out + (size_t)row * 256 + f2 * 2) = o;
}

// ---------------------------------------------------------------------------
extern "C" void kernel_launch(void* const* d_in, const int* in_sizes, int n_in,
                              void* d_out, int out_size, void* d_ws, size_t ws_size,
                              hipStream_t stream) {
  (void)in_sizes; (void)n_in; (void)out_size; (void)ws_size;
  const float* X  = (const float*)d_in[0];
  const float* WQ = (const float*)d_in[1];
  const float* bQ = (const float*)d_in[2];
  const float* WK = (const float*)d_in[3];
  const float* bK = (const float*)d_in[4];
  const float* WV = (const float*)d_in[5];
  const float* bV = (const float*)d_in[6];
  float* out = (float*)d_out;
  char* ws = (char*)d_ws;

  // ws: Qb 4M | Kb 4M | Vt 4M | Qp 256K | Kp 256K | Wt 384K | Xb 4M |
  //     ml 512K | Op 32M
  u16*   Qb = (u16*)(ws);
  u16*   Kb = (u16*)(ws + ((size_t)4 << 20));
  u16*   Vt = (u16*)(ws + ((size_t)8 << 20));
  u16*   Qp = (u16*)(ws + ((size_t)12 << 20));
  u16*   Kp = (u16*)(ws + ((size_t)12 << 20) + 262144);
  u16*   Wt = (u16*)(ws + ((size_t)12 << 20) + 524288);
  u16*   Xb = (u16*)(ws + ((size_t)12 << 20) + 524288 + 393216);
  float* ml = (float*)(ws + ((size_t)16 << 20) + 524288 + 393216);
  u16*   Op = (u16*)(ws + ((size_t)16 << 20) + 524288 + 393216 + 524288);

  xb_kernel<<<dim3(NTOK / 8), dim3(256), 0, stream>>>(X, Xb, Qp, Kp);
  wprep_kernel<<<dim3(768), dim3(256), 0, stream>>>(WQ, WK, WV, Wt);
  qkv_kernel<<<dim3(64, 12), dim3(256), 0, stream>>>(Xb, Wt, bQ, bK, bV,
                                                     Qb, Kb, Vt);
  attn_kernel<<<dim3(KSPLIT, NTOK / 256), dim3(512), 0, stream>>>(
      Qb, Kb, Vt, Qp, Kp, Op, ml);
  combine_kernel<<<dim3(NTOK / 2), dim3(256), 0, stream>>>(X, Op, ml, out);
}

// Round 7
// 200.683 us; speedup vs baseline: 1.4330x; 1.0252x over previous
//
#include <hip/hip_runtime.h>
#include <hip/hip_bf16.h>
#include <stdint.h>

#define NTOK 8192
#define XSTRIDE 259
#define LOG2E 1.4426950408889634f
#define DECC (-3.4712336270551023f)   /* -4 + log2(log2 e) */
#define KSPLIT 8
#define SPLEN (NTOK / KSPLIT)   /* 1024 */
#define BN 64
#define ITERS (SPLEN / BN)      /* 16 */

typedef __bf16 bf16x8 __attribute__((ext_vector_type(8)));
typedef float f32x4 __attribute__((ext_vector_type(4)));
typedef float f32x16 __attribute__((ext_vector_type(16)));
typedef unsigned short u16;

union BF8 { u16 u[8]; bf16x8 v; };
union PW  { uint32_t u[4]; bf16x8 v; };

__device__ __forceinline__ u16 f2bf(float f) {
  uint32_t u = __float_as_uint(f);
  u += 0x7FFFu + ((u >> 16) & 1u);
  return (u16)(u >> 16);
}
__device__ __forceinline__ float bf2f(u16 h) {
  return __uint_as_float(((uint32_t)h) << 16);
}
__device__ __forceinline__ float exp2_hw(float x) {
  float r; asm("v_exp_f32 %0, %1" : "=v"(r) : "v"(x)); return r;
}
__device__ __forceinline__ f32x4 mfma16(bf16x8 a, bf16x8 b, f32x4 c) {
  return __builtin_amdgcn_mfma_f32_16x16x32_bf16(a, b, c, 0, 0, 0);
}
__device__ __forceinline__ f32x16 mfma32(bf16x8 a, bf16x8 b, f32x16 c) {
  return __builtin_amdgcn_mfma_f32_32x32x16_bf16(a, b, c, 0, 0, 0);
}
__device__ __forceinline__ void async16(const void* g, void* l) {
  __builtin_amdgcn_global_load_lds(
      (const __attribute__((address_space(1))) uint32_t*)g,
      (__attribute__((address_space(3))) uint32_t*)l, 16, 0, 0);
}
__device__ __forceinline__ void bsplit(float v, u16& h, u16& l) {
  h = f2bf(v);
  l = f2bf(v - bf2f(h));
}

// ---------------------------------------------------------------------------
// Kernel 0 (fused prep): blocks 0..1023 = X->bf16 + position vectors;
//  blocks 1024..1047 = W^T transpose via LDS (coalesced both sides;
//  old wprep read W at 1KB lane stride).
// ---------------------------------------------------------------------------
__global__ __launch_bounds__(256) void prep_kernel(
    const float* __restrict__ X, const float* __restrict__ WQ,
    const float* __restrict__ WK, const float* __restrict__ WV,
    u16* __restrict__ Xb, u16* __restrict__ Qp, u16* __restrict__ Kp,
    u16* __restrict__ Wt) {
  const int bid = blockIdx.x;
  const int t = threadIdx.x;
  if (bid < NTOK / 8) {
    // ---- xb part ----
    const int row = bid * 8 + (t >> 5);
    const int c0 = (t & 31) * 8;
    const float* xp = X + (size_t)row * XSTRIDE + c0;
    union { u16 u[8]; uint4 v; } o;
#pragma unroll
    for (int j = 0; j < 8; ++j) o.u[j] = f2bf(xp[j]);
    *(uint4*)(Xb + (size_t)row * 256 + c0) = o.v;

    if (t < 8) {
      const int r = bid * 8 + t;
      const float* pp = X + (size_t)r * XSTRIDE + 256;
      const float x = pp[0], y = pp[1], z = pp[2];
      const float w = 0.5f * (x * x + y * y + z * z);
      u16 xh, xl, yh, yl, zh, zl, wh, wl;
      bsplit(x, xh, xl); bsplit(y, yh, yl); bsplit(z, zh, zl);
      bsplit(w, wh, wl);
      const u16 one = 0x3F80u;
      const u16 SGN = 0x8000u;
      union { u16 u[16]; uint4 v4[2]; } uq, uk;
      uq.u[0] = wh;  uk.u[0] = one;
      uq.u[1] = wl;  uk.u[1] = one;
      uq.u[2] = one; uk.u[2] = wh;
      uq.u[3] = one; uk.u[3] = wl;
      uq.u[4] = (u16)(xh ^ SGN); uk.u[4] = xh;
      uq.u[5] = (u16)(xh ^ SGN); uk.u[5] = xl;
      uq.u[6] = (u16)(xl ^ SGN); uk.u[6] = xh;
      uq.u[7] = (u16)(yh ^ SGN); uk.u[7] = yh;
      uq.u[8] = (u16)(yh ^ SGN); uk.u[8] = yl;
      uq.u[9] = (u16)(yl ^ SGN); uk.u[9] = yh;
      uq.u[10] = (u16)(zh ^ SGN); uk.u[10] = zh;
      uq.u[11] = (u16)(zh ^ SGN); uk.u[11] = zl;
      uq.u[12] = (u16)(zl ^ SGN); uk.u[12] = zh;
      uq.u[13] = 0; uk.u[13] = 0;
      uq.u[14] = 0; uk.u[14] = 0;
      uq.u[15] = 0; uk.u[15] = 0;
      ((uint4*)Qp)[r * 2] = uq.v4[0];
      ((uint4*)Qp)[r * 2 + 1] = uq.v4[1];
      ((uint4*)Kp)[r * 2] = uk.v4[0];
      ((uint4*)Kp)[r * 2 + 1] = uk.v4[1];
    }
  } else {
    // ---- wprep part: Wt[o_global][k] = bf16(W[k][o]) ----
    __shared__ u16 T[32 * 264];       // 32 o x 256 k (+8 pad)
    const int b2 = bid - NTOK / 8;    // 0..23
    const int which = b2 >> 3, ob = b2 & 7;
    const float* W = (which == 0) ? WQ : ((which == 1) ? WK : WV);
    const int kk = t >> 5, oo = t & 31;
#pragma unroll
    for (int kc = 0; kc < 32; ++kc) {
      const int k = kc * 8 + kk;
      T[oo * 264 + k] = f2bf(W[(size_t)k * 256 + ob * 32 + oo]);
    }
    __syncthreads();
#pragma unroll
    for (int i = 0; i < 4; ++i) {
      int chn = i * 256 + t;          // 1024 chunks of 16B
      int o2 = chn >> 5, s = chn & 31;
      uint4 d = *(const uint4*)(T + o2 * 264 + s * 8);
      *(uint4*)(Wt + (size_t)(which * 256 + ob * 32 + o2) * 256 + s * 8) = d;
    }
  }
}

// ---------------------------------------------------------------------------
// Kernel 1: QKV projection, regridded (128 rowblocks x 3 matrices).
//  R6 defect: 12 col-chunk blocks re-read the same Xb rows (48MB, 4x
//  redundant) and each block ran stage->drain->compute->store serially.
//  Now: block = 64 rows x all 256 cols of ONE matrix; xa loaded once;
//  4 col-chunks with DOUBLE-BUFFERED W staging (compute c overlaps DMA c+1).
//  C-tile bounced through the dead LDS buffer for coalesced dwordx4 stores
//  (R6-validated). Xb traffic 48->12MB; W 1.5MB source is L2-resident.
// ---------------------------------------------------------------------------
__global__ __launch_bounds__(256) void qkv_kernel(
    const u16* __restrict__ Xb, const u16* __restrict__ Wt,
    const float* __restrict__ bQ, const float* __restrict__ bK,
    const float* __restrict__ bV,
    u16* __restrict__ Qb, u16* __restrict__ Kb, u16* __restrict__ Vt) {
  __shared__ u16 wt[2][64 * 256];   // 32KB x2: W dbuf; dead buf = C bounce
  const int tid = threadIdx.x;
  const int lane = tid & 63;
  const int wave = tid >> 6;
  const int l15 = lane & 15;
  const int q4 = lane >> 4;
  const int rb = blockIdx.x;         // 0..127 (64-row blocks)
  const int which = blockIdx.y;      // 0..2
  const float* bias = (which == 0) ? bQ : ((which == 1) ? bK : bV);
  const int grow0 = rb * 64;

  // xa: this block's 64 rows, once (wave w owns rows wave*16 + l15)
  bf16x8 xa[8];
  {
    const int row = grow0 + wave * 16 + l15;
#pragma unroll
    for (int kc = 0; kc < 8; ++kc)
      xa[kc] = *(const bf16x8*)(Xb + (size_t)row * 256 + kc * 32 + q4 * 8);
  }

#define STAGEW(C_, B_)                                                        \
  do {                                                                        \
    const u16* Wsrc = Wt + (size_t)(which * 256 + (C_) * 64) * 256;           \
    const int rb0 = wave * 16;                                                \
    _Pragma("unroll")                                                         \
    for (int i = 0; i < 8; ++i) {                                             \
      int r = rb0 + i * 2 + (lane >> 5);                                      \
      int cc = (lane & 31) ^ (r & 7);                                         \
      async16(Wsrc + (size_t)r * 256 + cc * 8, &wt[B_][(rb0 + i * 2) * 256]); \
    }                                                                         \
  } while (0)

  STAGEW(0, 0);

#pragma unroll 1
  for (int c = 0; c < 4; ++c) {
    const int cur = c & 1;
    const int c0 = c * 64;
    asm volatile("s_waitcnt vmcnt(0)" ::: "memory");
    __syncthreads();
    if (c < 3) STAGEW(c + 1, cur ^ 1);

    f32x4 acc[4];
#pragma unroll
    for (int nt = 0; nt < 4; ++nt) acc[nt] = (f32x4){0.f, 0.f, 0.f, 0.f};
#pragma unroll
    for (int kc = 0; kc < 8; ++kc) {
#pragma unroll
      for (int nt = 0; nt < 4; ++nt) {
        bf16x8 wf = *(const bf16x8*)(&wt[cur][(nt * 16 + l15) * 256 +
                                     (((kc * 4 + q4) ^ (l15 & 7)) * 8)]);
        acc[nt] = mfma16(xa[kc], wf, acc[nt]);
      }
    }
    float bc[4];
#pragma unroll
    for (int nt = 0; nt < 4; ++nt) bc[nt] = bias[c0 + nt * 16 + l15];

    __syncthreads();          // all waves done reading wt[cur]
    u16* smem = &wt[cur][0];  // dead W buffer -> C-tile bounce

    if (which == 2) {
      // transposed tile Tv[col 64][row 64 + pad8]
#pragma unroll
      for (int nt = 0; nt < 4; ++nt) {
        const int lcol = nt * 16 + l15;
        union { u16 u[4]; uint2 w; } p;
#pragma unroll
        for (int r = 0; r < 4; ++r) p.u[r] = f2bf(acc[nt][r] + bc[nt]);
        *(uint2*)(smem + lcol * 72 + wave * 16 + q4 * 4) = p.w;
      }
      __syncthreads();
#pragma unroll
      for (int i = 0; i < 2; ++i) {
        int chn = i * 256 + tid;        // 512 chunks of 16B
        int lcol = chn >> 3, s = chn & 7;
        uint4 d = *(const uint4*)(smem + lcol * 72 + s * 8);
        *(uint4*)(Vt + (size_t)(c0 + lcol) * NTOK + grow0 + s * 8) = d;
      }
    } else {
      // row-major tile T[row 64][col 64 + pad8]
#pragma unroll
      for (int nt = 0; nt < 4; ++nt)
#pragma unroll
        for (int r = 0; r < 4; ++r)
          smem[(wave * 16 + q4 * 4 + r) * 72 + nt * 16 + l15] =
              f2bf(acc[nt][r] + bc[nt]);
      __syncthreads();
#pragma unroll
      for (int i = 0; i < 2; ++i) {
        int chn = i * 256 + tid;        // 512 chunks of 16B
        int lrow = chn >> 3, g = chn & 7;
        uint4 d = *(const uint4*)(smem + lrow * 72 + g * 8);
        int grow = grow0 + lrow, gc = c0 + g * 8;
        if (which == 1)
          *(uint4*)(Kb + (size_t)grow * 256 + gc) = d;
        else
          *(uint4*)(Qb + (size_t)((grow >> 5) * 16 + (gc >> 4)) * 512 +
                    ((gc >> 3) & 1) * 256 + (grow & 31) * 8) = d;
      }
    }
  }
#undef STAGEW
}

// ---------------------------------------------------------------------------
// Kernel 2: flash attention — UNCHANGED from R6 (control; best measured
//  structure: M=32/wave, 32x32x16 MFMA, 8-wave blocks, BN=64 dbuf,
//  1 block/CU, split-per-XCD). Structurally pinned at ~119us by the
//  lockstep-phase / 2-waves-per-SIMD register cap; frozen this round.
// ---------------------------------------------------------------------------
__global__ __launch_bounds__(512, 2) void attn_kernel(
    const u16* __restrict__ Qb, const u16* __restrict__ Kb,
    const u16* __restrict__ Vt, const u16* __restrict__ Qp,
    const u16* __restrict__ Kp, u16* __restrict__ Op,
    float* __restrict__ ml) {
  __shared__ u16 kbuf[2][BN * 256];               // 32 KB x2  [key][256]
  __shared__ u16 vbuf[2][256 * BN];               // 32 KB x2  [feat][64]
  __shared__ u16 kpbuf[2][BN * 16];               // 2 KB x2   [key][16]

  const int tid = threadIdx.x;
  const int lane = tid & 63;
  const int wave = tid >> 6;
  const int l31 = lane & 31;
  const int h5 = lane >> 5;
  const int sp = blockIdx.x;
  const int rb = blockIdx.y;
  const int q0 = rb * 256;
  const int wrow = wave * 32;

#define STAGE(T, S_)                                                          \
  do {                                                                        \
    const int key0_ = sp * SPLEN + (T) * BN;                                  \
    _Pragma("unroll")                                                         \
    for (int j = 0; j < 4; ++j) {                                             \
      int r = wave * 8 + j * 2 + (lane >> 5);                                 \
      int c = (lane & 31) ^ (r & 7);                                          \
      async16(Kb + (size_t)(key0_ + r) * 256 + c * 8,                         \
              &kbuf[S_][(wave * 8 + j * 2) * 256]);                           \
    }                                                                         \
    _Pragma("unroll")                                                         \
    for (int j = 0; j < 4; ++j) {                                             \
      int f = wave * 32 + j * 8 + (lane >> 3);                                \
      int c = (lane & 7) ^ (f & 7);                                           \
      async16(Vt + (size_t)f * NTOK + key0_ + c * 8,                          \
              &vbuf[S_][(wave * 32 + j * 8) * BN]);                           \
    }                                                                         \
    if (wave == 0) {                                                          \
      _Pragma("unroll")                                                       \
      for (int hh = 0; hh < 2; ++hh)                                          \
        async16(Kp + (size_t)(key0_ + hh * 32 + (lane >> 1)) * 16 +           \
                    (lane & 1) * 8,                                           \
                &kpbuf[S_][hh * 32 * 16]);                                    \
    }                                                                         \
  } while (0)

  // ---- Q fragments (loop-invariant, coalesced from frag-layout Qb) ----
  const int rb32 = rb * 8 + wave;
  bf16x8 qa[16];
#pragma unroll
  for (int kc = 0; kc < 16; ++kc)
    qa[kc] = *(const bf16x8*)(Qb + ((size_t)(rb32 * 16 + kc) * 64 + lane) * 8);

  // position B-fragment for this lane's qrow (col = lane&31 in S^T layout)
  const bf16x8 qp = *(const bf16x8*)(Qp + (size_t)(q0 + wrow + l31) * 16 +
                                     h5 * 8);

  f32x16 O[8];
#pragma unroll
  for (int ft = 0; ft < 8; ++ft)
#pragma unroll
    for (int r = 0; r < 16; ++r) O[ft][r] = 0.f;
  float lrow = 0.f;

  const int swz = l31 & 7;

  STAGE(0, 0);

#pragma unroll 1
  for (int t = 0; t < ITERS; ++t) {
    const int slot = t & 1;
    asm volatile("s_waitcnt vmcnt(0)" ::: "memory");
    __builtin_amdgcn_s_barrier();
    if (t + 1 < ITERS) STAGE(t + 1, slot ^ 1);

#pragma unroll
    for (int sub = 0; sub < 2; ++sub) {
      // ---- T = decay-exponent MFMA ----
      f32x16 T;
#pragma unroll
      for (int r = 0; r < 16; ++r) T[r] = 0.f;
      {
        bf16x8 kpf = *(const bf16x8*)(&kpbuf[slot][(sub * 32 + l31) * 16 +
                                      h5 * 8]);
        T = mfma32(kpf, qp, T);
      }

      // ---- S^T = K Q^T : D[key][qrow], 32 keys x 32 rows ----
      f32x16 S;
#pragma unroll
      for (int r = 0; r < 16; ++r) S[r] = 0.f;
      __builtin_amdgcn_s_setprio(1);
#pragma unroll
      for (int kc = 0; kc < 16; ++kc) {
        bf16x8 kf = *(const bf16x8*)(&kbuf[slot][(sub * 32 + l31) * 256 +
                                     (((2 * kc + h5) ^ swz) * 8)]);
        S = mfma32(kf, qa[kc], S);
      }
      __builtin_amdgcn_s_setprio(0);

      // ---- softmax: dec = exp2(-t*log2e + DECC); p = exp2(S*dec) ----
#pragma unroll
      for (int r = 0; r < 16; ++r) {
        float dec = exp2_hw(fmaf(T[r], -LOG2E, DECC));
        float p = exp2_hw(S[r] * dec);
        S[r] = p;
        lrow += p;
      }

      // ---- pack P to bf16 A-frags in-register ----
      uint32_t w0, w1, w2, w3, w4, w5, w6, w7;
      asm("v_cvt_pk_bf16_f32 %0, %1, %2" : "=v"(w0) : "v"(S[0]),  "v"(S[1]));
      asm("v_cvt_pk_bf16_f32 %0, %1, %2" : "=v"(w1) : "v"(S[2]),  "v"(S[3]));
      asm("v_cvt_pk_bf16_f32 %0, %1, %2" : "=v"(w2) : "v"(S[4]),  "v"(S[5]));
      asm("v_cvt_pk_bf16_f32 %0, %1, %2" : "=v"(w3) : "v"(S[6]),  "v"(S[7]));
      asm("v_cvt_pk_bf16_f32 %0, %1, %2" : "=v"(w4) : "v"(S[8]),  "v"(S[9]));
      asm("v_cvt_pk_bf16_f32 %0, %1, %2" : "=v"(w5) : "v"(S[10]), "v"(S[11]));
      asm("v_cvt_pk_bf16_f32 %0, %1, %2" : "=v"(w6) : "v"(S[12]), "v"(S[13]));
      asm("v_cvt_pk_bf16_f32 %0, %1, %2" : "=v"(w7) : "v"(S[14]), "v"(S[15]));
      asm volatile("v_permlane32_swap_b32 %0, %1" : "+v"(w2), "+v"(w0));
      asm volatile("v_permlane32_swap_b32 %0, %1" : "+v"(w3), "+v"(w1));
      asm volatile("v_permlane32_swap_b32 %0, %1" : "+v"(w6), "+v"(w4));
      asm volatile("v_permlane32_swap_b32 %0, %1" : "+v"(w7), "+v"(w5));
      PW pa0, pa1;
      pa0.u[0] = w0; pa0.u[1] = w1; pa0.u[2] = w2; pa0.u[3] = w3;
      pa1.u[0] = w4; pa1.u[1] = w5; pa1.u[2] = w6; pa1.u[3] = w7;

      // ---- O += P V (full 256 features, 8 ft-blocks of 32) ----
      __builtin_amdgcn_s_setprio(1);
#pragma unroll
      for (int kh = 0; kh < 2; ++kh) {
        const bf16x8 pa = kh ? pa1.v : pa0.v;
        const int khh = sub * 2 + kh;
#pragma unroll
        for (int ft = 0; ft < 8; ++ft) {
          bf16x8 vf = *(const bf16x8*)(&vbuf[slot][(ft * 32 + l31) * BN +
                                       (((2 * khh + h5) ^ swz) * 8)]);
          O[ft] = mfma32(pa, vf, O[ft]);
        }
      }
      __builtin_amdgcn_s_setprio(0);
    }
  }

  // ---- epilogue ----
  float lsum = lrow + __shfl_xor(lrow, 32);
#pragma unroll
  for (int ft = 0; ft < 8; ++ft)
#pragma unroll
    for (int r = 0; r < 16; ++r) {
      int row = q0 + wrow + (r & 3) + 8 * (r >> 2) + 4 * h5;
      Op[((size_t)sp * NTOK + row) * 256 + ft * 32 + l31] = f2bf(O[ft][r]);
    }
  if (lane < 32)
    ml[sp * NTOK + q0 + wrow + lane] = lsum;
#undef STAGE
}

// ---------------------------------------------------------------------------
// Kernel 3: combine splits, vectorized (uint = 2 bf16 loads, float2 store).
// ---------------------------------------------------------------------------
__global__ __launch_bounds__(256) void combine_kernel(
    const float* __restrict__ X, const u16* __restrict__ Op,
    const float* __restrict__ ml, float* __restrict__ out) {
  const int row = blockIdx.x * 2 + (threadIdx.x >> 7);
  const int f2 = threadIdx.x & 127;
  float den = 1.f, n0 = 0.f, n1 = 0.f;
#pragma unroll
  for (int s = 0; s < KSPLIT; ++s) {
    den += ml[s * NTOK + row];
    uint32_t v = *(const uint32_t*)(Op + ((size_t)s * NTOK + row) * 256 +
                                    f2 * 2);
    n0 += bf2f((u16)v);
    n1 += bf2f((u16)(v >> 16));
  }
  const float inv = 1.f / den;
  float2 o;
  o.x = n0 * inv + X[(size_t)row * XSTRIDE + f2 * 2];
  o.y = n1 * inv + X[(size_t)row * XSTRIDE + f2 * 2 + 1];
  *(float2*)(out + (size_t)row * 256 + f2 * 2) = o;
}

// ---------------------------------------------------------------------------
extern "C" void kernel_launch(void* const* d_in, const int* in_sizes, int n_in,
                              void* d_out, int out_size, void* d_ws, size_t ws_size,
                              hipStream_t stream) {
  (void)in_sizes; (void)n_in; (void)out_size; (void)ws_size;
  const float* X  = (const float*)d_in[0];
  const float* WQ = (const float*)d_in[1];
  const float* bQ = (const float*)d_in[2];
  const float* WK = (const float*)d_in[3];
  const float* bK = (const float*)d_in[4];
  const float* WV = (const float*)d_in[5];
  const float* bV = (const float*)d_in[6];
  float* out = (float*)d_out;
  char* ws = (char*)d_ws;

  // ws: Qb 4M | Kb 4M | Vt 4M | Qp 256K | Kp 256K | Wt 384K | Xb 4M |
  //     ml 512K | Op 32M
  u16*   Qb = (u16*)(ws);
  u16*   Kb = (u16*)(ws + ((size_t)4 << 20));
  u16*   Vt = (u16*)(ws + ((size_t)8 << 20));
  u16*   Qp = (u16*)(ws + ((size_t)12 << 20));
  u16*   Kp = (u16*)(ws + ((size_t)12 << 20) + 262144);
  u16*   Wt = (u16*)(ws + ((size_t)12 << 20) + 524288);
  u16*   Xb = (u16*)(ws + ((size_t)12 << 20) + 524288 + 393216);
  float* ml = (float*)(ws + ((size_t)16 << 20) + 524288 + 393216);
  u16*   Op = (u16*)(ws + ((size_t)16 << 20) + 524288 + 393216 + 524288);

  prep_kernel<<<dim3(NTOK / 8 + 24), dim3(256), 0, stream>>>(
      X, WQ, WK, WV, Xb, Qp, Kp, Wt);
  qkv_kernel<<<dim3(128, 3), dim3(256), 0, stream>>>(Xb, Wt, bQ, bK, bV,
                                                     Qb, Kb, Vt);
  attn_kernel<<<dim3(KSPLIT, NTOK / 256), dim3(512), 0, stream>>>(
      Qb, Kb, Vt, Qp, Kp, Op, ml);
  combine_kernel<<<dim3(NTOK / 2), dim3(256), 0, stream>>>(X, Op, ml, out);
}